// Round 10
// baseline (663.970 us; speedup 1.0000x reference)
//
#include <hip/hip_runtime.h>
#include <math.h>

// T=4096, M=512, NH=8, HD=64, FF=2048, NL=2, NI=256 (16 tok/seg), NO=32 (8 seg/outer)

typedef float f32x4 __attribute__((ext_vector_type(4)));
typedef __bf16 bf16x8 __attribute__((ext_vector_type(8)));

__device__ __forceinline__ unsigned short f2bf(float x) {
  unsigned int u = __builtin_bit_cast(unsigned int, x);
  u += 0x7FFFu + ((u >> 16) & 1u);
  return (unsigned short)(u >> 16);
}
__device__ __forceinline__ float bf2f(unsigned short u) {
  unsigned int x = ((unsigned int)u) << 16;
  return __builtin_bit_cast(float, x);
}
// pack two f32 -> two bf16 (RTNE) in one instruction
__device__ __forceinline__ unsigned int pk_bf16(float a, float b) {
  unsigned int r;
  asm("v_cvt_pk_bf16_f32 %0, %1, %2" : "=v"(r) : "v"(a), "v"(b));
  return r;
}

__device__ __forceinline__ float wave_sum64(float v) {
#pragma unroll
  for (int o = 32; o > 0; o >>= 1) v += __shfl_xor(v, o);
  return v;
}

// XOR swizzle for LDS tiles with 128-byte rows (64 bf16/row).
__device__ __forceinline__ int swz(int byte) {
  return byte ^ (((byte >> 7) & 7) << 4);
}
// XOR swizzle for LDS tiles with 256-byte rows (128 bf16/row).
__device__ __forceinline__ int swz256(int byte) {
  return byte ^ (((byte >> 8) & 7) << 4);
}

// ============ bf16 MFMA GEMM: C[M,N] = act(A[M,K] @ B[N,K]^T + bias) ============
// ACT: 0 none, 1 relu, 2 tanh, 3 sigmoid, 4 col<128?tanh:sigmoid (fused gate)
// VSPLIT: cols >= 1024 go to VT[col-1024][row] (bf16, packed 4-row stores).
template<int ACT, int OUTBF, int VSPLIT>
__global__ __launch_bounds__(256) void mgemm(
    const unsigned short* __restrict__ A, const unsigned short* __restrict__ B,
    const float* __restrict__ bias, float* __restrict__ Cf,
    unsigned short* __restrict__ Cb, unsigned short* __restrict__ VT,
    int M, int N, int K)
{
  __shared__ __align__(16) unsigned short As[128 * 64];
  __shared__ __align__(16) unsigned short Bs[128 * 64];
  const int tid = threadIdx.x;
  const int wid = tid >> 6, lane = tid & 63;
  const int wm = wid >> 1, wn = wid & 1;
  const int l15 = lane & 15, l4 = lane >> 4;
  const int m0 = blockIdx.y * 128, n0 = blockIdx.x * 128;
  const int srow = tid >> 3;
  const int scol = (tid & 7) * 8;

  f32x4 acc[4][4] = {};

  bf16x8 ra[4], rb[4];
#pragma unroll
  for (int i = 0; i < 4; i++) {
    ra[i] = *(const bf16x8*)&A[(size_t)(m0 + srow + i * 32) * K + scol];
    rb[i] = *(const bf16x8*)&B[(size_t)(n0 + srow + i * 32) * K + scol];
  }

  for (int k0 = 0; k0 < K; k0 += 64) {
    __syncthreads();   // all waves done reading previous LDS tile
#pragma unroll
    for (int i = 0; i < 4; i++) {
      int byte = (srow + i * 32) * 128 + scol * 2;
      *(bf16x8*)((char*)As + swz(byte)) = ra[i];
      *(bf16x8*)((char*)Bs + swz(byte)) = rb[i];
    }
    __syncthreads();   // LDS ready
    if (k0 + 64 < K) { // prefetch next tile; latency hides under MFMA below
#pragma unroll
      for (int i = 0; i < 4; i++) {
        ra[i] = *(const bf16x8*)&A[(size_t)(m0 + srow + i * 32) * K + k0 + 64 + scol];
        rb[i] = *(const bf16x8*)&B[(size_t)(n0 + srow + i * 32) * K + k0 + 64 + scol];
      }
    }
#pragma unroll
    for (int kc = 0; kc < 2; kc++) {
      bf16x8 af[4], bf_[4];
#pragma unroll
      for (int i = 0; i < 4; i++) {
        int byteA = (wm * 64 + i * 16 + l15) * 128 + kc * 64 + l4 * 16;
        af[i] = *(const bf16x8*)((const char*)As + swz(byteA));
        int byteB = (wn * 64 + i * 16 + l15) * 128 + kc * 64 + l4 * 16;
        bf_[i] = *(const bf16x8*)((const char*)Bs + swz(byteB));
      }
#pragma unroll
      for (int i = 0; i < 4; i++)
#pragma unroll
        for (int j = 0; j < 4; j++)
          acc[i][j] = __builtin_amdgcn_mfma_f32_16x16x32_bf16(af[i], bf_[j], acc[i][j], 0, 0, 0);
    }
  }
#pragma unroll
  for (int i = 0; i < 4; i++) {
#pragma unroll
    for (int j = 0; j < 4; j++) {
      int col = n0 + wn * 64 + j * 16 + l15;
      float bv = bias[col];
      if (VSPLIT && col >= 1024) {
        float x0 = acc[i][j][0] + bv, x1 = acc[i][j][1] + bv;
        float x2 = acc[i][j][2] + bv, x3 = acc[i][j][3] + bv;
        uint2 pv;
        pv.x = pk_bf16(x0, x1);
        pv.y = pk_bf16(x2, x3);
        int row0 = m0 + wm * 64 + i * 16 + l4 * 4;
        *(uint2*)&VT[(size_t)(col - 1024) * 4096 + row0] = pv;
      } else {
#pragma unroll
        for (int r = 0; r < 4; r++) {
          int row = m0 + wm * 64 + i * 16 + l4 * 4 + r;
          float x = acc[i][j][r] + bv;
          if (ACT == 1) x = fmaxf(x, 0.f);
          if (ACT == 2) x = tanhf(x);
          if (ACT == 3) x = 1.f / (1.f + expf(-x));
          if (ACT == 4) x = (col < 128) ? tanhf(x) : (1.f / (1.f + expf(-x)));
          if (OUTBF) Cb[(size_t)row * N + col] = f2bf(x);
          else       Cf[(size_t)row * N + col] = x;
        }
      }
    }
  }
}

// ============ MFMA flash attention: QBLK=128, lane-local softmax ============
// Bit-identical per-q-row numerics to round 9; each wave now owns TWO q-subtiles
// (rows w*16+l15 and 64+w*16+l15 of the 128-row block), so every Ks/VTs LDS
// fragment read feeds two MFMAs (halves the binding LDS-read traffic).
__global__ __launch_bounds__(256) void attn_mfma(
    const unsigned short* __restrict__ qkv, const unsigned short* __restrict__ VT,
    unsigned short* __restrict__ O)
{
  __shared__ __align__(16) unsigned short Ks[64 * 64];    // [k][d]   swizzled
  __shared__ __align__(16) unsigned short VTs[64 * 64];   // [d][k]   swizzled
  __shared__ __align__(16) unsigned short Ps[128 * 64];   // [q][k]   swizzled
  const int tid = threadIdx.x;
  const int w = tid >> 6, lane = tid & 63;
  const int l15 = lane & 15, l4 = lane >> 4;
  const int h = blockIdx.y, qt = blockIdx.x;
  const float C = 0.18033688011112042f;   // 0.125 * log2(e)

  // Q fragments for both q-subtiles (B operand: col = q = l15)
  bf16x8 qf[2][2];
#pragma unroll
  for (int s = 0; s < 2; s++)
#pragma unroll
    for (int kc = 0; kc < 2; kc++)
      qf[s][kc] = *(const bf16x8*)&qkv[(size_t)(qt * 128 + s * 64 + w * 16 + l15) * 1536 +
                                       h * 64 + kc * 32 + l4 * 8];

  f32x4 oaccT[2][4] = {};
  float m[2] = {-1e30f, -1e30f}, l[2] = {0.f, 0.f};

  const int sr = tid >> 3;
  const int sc = (tid & 7) * 8;
  const int vd = tid >> 2;            // 0..63
  const int vk0 = (tid & 3) * 16;     // 0,16,32,48

  const unsigned short* kp0 = qkv + (size_t)sr * 1536 + 512 + h * 64 + sc;
  const unsigned short* kp1 = kp0 + 32 * 1536;
  const unsigned short* vp = VT + (size_t)(h * 64 + vd) * 4096 + vk0;

  bf16x8 rk0 = *(const bf16x8*)kp0;
  bf16x8 rk1 = *(const bf16x8*)kp1;
  bf16x8 rv0 = *(const bf16x8*)vp;
  bf16x8 rv1 = *(const bf16x8*)(vp + 8);

  for (int kt = 0; kt < 64; kt++) {
    __syncthreads();   // previous tile fully consumed
    {
      int b0 = sr * 128 + sc * 2;
      *(bf16x8*)((char*)Ks + swz(b0)) = rk0;
      int b1 = (sr + 32) * 128 + sc * 2;
      *(bf16x8*)((char*)Ks + swz(b1)) = rk1;
      int vb0 = vd * 128 + vk0 * 2;
      *(bf16x8*)((char*)VTs + swz(vb0)) = rv0;
      *(bf16x8*)((char*)VTs + swz(vb0 + 16)) = rv1;
    }
    __syncthreads();   // LDS ready
    if (kt < 63) {     // prefetch next tile (bit-exact; hides HBM latency)
      kp0 += 64 * 1536; kp1 += 64 * 1536; vp += 64;
      rk0 = *(const bf16x8*)kp0;
      rk1 = *(const bf16x8*)kp1;
      rv0 = *(const bf16x8*)vp;
      rv1 = *(const bf16x8*)(vp + 8);
    }

    // S^T for both q-subtiles: each kf fragment read once, used twice
    f32x4 st[2][4] = {};
    __builtin_amdgcn_s_setprio(1);
#pragma unroll
    for (int kc = 0; kc < 2; kc++) {
#pragma unroll
      for (int nb = 0; nb < 4; nb++) {
        int byte = (nb * 16 + l15) * 128 + kc * 64 + l4 * 16;
        bf16x8 kf = *(const bf16x8*)((const char*)Ks + swz(byte));
        st[0][nb] = __builtin_amdgcn_mfma_f32_16x16x32_bf16(kf, qf[0][kc], st[0][nb], 0, 0, 0);
        st[1][nb] = __builtin_amdgcn_mfma_f32_16x16x32_bf16(kf, qf[1][kc], st[1][nb], 0, 0, 0);
      }
    }
    __builtin_amdgcn_s_setprio(0);

    // lane-local online softmax per q-subtile (identical sequence per q-row)
#pragma unroll
    for (int s = 0; s < 2; s++) {
      float tm = -1e30f;
#pragma unroll
      for (int nb = 0; nb < 4; nb++)
#pragma unroll
        for (int r = 0; r < 4; r++) tm = fmaxf(tm, st[s][nb][r]);
      tm = fmaxf(tm, __shfl_xor(tm, 16));
      tm = fmaxf(tm, __shfl_xor(tm, 32));
      float mn = fmaxf(m[s], tm);
      float alpha = exp2f((m[s] - mn) * C);
      float e[4][4];
      float ps = 0.f;
#pragma unroll
      for (int nb = 0; nb < 4; nb++)
#pragma unroll
        for (int r = 0; r < 4; r++) {
          e[nb][r] = exp2f((st[s][nb][r] - mn) * C);
          ps += e[nb][r];
        }
      ps += __shfl_xor(ps, 16);
      ps += __shfl_xor(ps, 32);
      l[s] = l[s] * alpha + ps;
      m[s] = mn;
#pragma unroll
      for (int nb = 0; nb < 4; nb++) oaccT[s][nb] *= alpha;

      // P rows -> Ps[q][k] (lane writes its own q-row; wave-local, no barrier)
#pragma unroll
      for (int nb = 0; nb < 4; nb++) {
        uint2 pr;
        pr.x = pk_bf16(e[nb][0], e[nb][1]);
        pr.y = pk_bf16(e[nb][2], e[nb][3]);
        int byte = (s * 64 + w * 16 + l15) * 128 + (nb * 16 + l4 * 4) * 2;
        *(uint2*)((char*)Ps + swz(byte)) = pr;
      }
    }

    // O^T += mfma(A=V^T, B=P): each vf fragment read once, used twice
#pragma unroll
    for (int kc = 0; kc < 2; kc++) {
      int bp0 = (w * 16 + l15) * 128 + kc * 64 + l4 * 16;
      bf16x8 pb0 = *(const bf16x8*)((const char*)Ps + swz(bp0));
      int bp1 = (64 + w * 16 + l15) * 128 + kc * 64 + l4 * 16;
      bf16x8 pb1 = *(const bf16x8*)((const char*)Ps + swz(bp1));
      __builtin_amdgcn_s_setprio(1);
#pragma unroll
      for (int nb = 0; nb < 4; nb++) {
        int bv = (nb * 16 + l15) * 128 + kc * 64 + l4 * 16;
        bf16x8 vf = *(const bf16x8*)((const char*)VTs + swz(bv));
        oaccT[0][nb] = __builtin_amdgcn_mfma_f32_16x16x32_bf16(vf, pb0, oaccT[0][nb], 0, 0, 0);
        oaccT[1][nb] = __builtin_amdgcn_mfma_f32_16x16x32_bf16(vf, pb1, oaccT[1][nb], 0, 0, 0);
      }
      __builtin_amdgcn_s_setprio(0);
    }
  }

  // epilogue: in-lane 1/l, packed 8-byte stores
#pragma unroll
  for (int s = 0; s < 2; s++) {
    float linv = 1.f / l[s];
    int row = qt * 128 + s * 64 + w * 16 + l15;
#pragma unroll
    for (int nb = 0; nb < 4; nb++) {
      uint2 ov;
      ov.x = pk_bf16(oaccT[s][nb][0] * linv, oaccT[s][nb][1] * linv);
      ov.y = pk_bf16(oaccT[s][nb][2] * linv, oaccT[s][nb][3] * linv);
      int col = h * 64 + nb * 16 + l4 * 4;
      *(uint2*)&O[(size_t)row * 512 + col] = ov;
    }
  }
}

// ---------------- fp32 GEMM (tiny stage-2 gating) ----------------
template<int ACT>
__global__ __launch_bounds__(256) void gemm_bias(
    const float* __restrict__ A, const float* __restrict__ B,
    const float* __restrict__ bias, float* __restrict__ C,
    int M, int N, int K)
{
  __shared__ float As[16][68];
  __shared__ float Bs[16][68];
  const int tid = threadIdx.x;
  const int tx = tid & 15, ty = tid >> 4;
  const int m0 = blockIdx.y * 64, n0 = blockIdx.x * 64;
  const int lr = tid >> 2;
  const int lk = (tid & 3) * 4;
  float acc[4][4] = {};
  for (int k0 = 0; k0 < K; k0 += 16) {
    __syncthreads();
    float4 av = *(const float4*)&A[(size_t)(m0 + lr) * K + k0 + lk];
    float4 bv = *(const float4*)&B[(size_t)(n0 + lr) * K + k0 + lk];
    As[lk + 0][lr] = av.x; As[lk + 1][lr] = av.y; As[lk + 2][lr] = av.z; As[lk + 3][lr] = av.w;
    Bs[lk + 0][lr] = bv.x; Bs[lk + 1][lr] = bv.y; Bs[lk + 2][lr] = bv.z; Bs[lk + 3][lr] = bv.w;
    __syncthreads();
#pragma unroll
    for (int k = 0; k < 16; k++) {
      float a[4], b[4];
#pragma unroll
      for (int i = 0; i < 4; i++) a[i] = As[k][ty * 4 + i];
#pragma unroll
      for (int j = 0; j < 4; j++) b[j] = Bs[k][tx * 4 + j];
#pragma unroll
      for (int i = 0; i < 4; i++)
#pragma unroll
        for (int j = 0; j < 4; j++)
          acc[i][j] = fmaf(a[i], b[j], acc[i][j]);
    }
  }
#pragma unroll
  for (int i = 0; i < 4; i++)
#pragma unroll
    for (int j = 0; j < 4; j++) {
      float x = acc[i][j] + bias[n0 + tx * 4 + j];
      if (ACT == 1) x = fmaxf(x, 0.f);
      if (ACT == 2) x = tanhf(x);
      if (ACT == 3) x = 1.f / (1.f + expf(-x));
      C[(size_t)(m0 + ty * 4 + i) * N + n0 + tx * 4 + j] = x;
    }
}

// ---------------- LayerNorm(x + res), writes f32 + bf16 ----------------
__global__ __launch_bounds__(64) void residual_ln(
    const float* __restrict__ x, const float* __restrict__ res,
    const float* __restrict__ g, const float* __restrict__ b,
    float* __restrict__ out, unsigned short* __restrict__ out_bf)
{
  const int row = blockIdx.x, lane = threadIdx.x;
  const float* xp = x + (size_t)row * 512;
  const float* rp = res + (size_t)row * 512;
  float v[8];
  float s = 0.f;
#pragma unroll
  for (int i = 0; i < 8; i++) { v[i] = xp[lane + 64 * i] + rp[lane + 64 * i]; s += v[i]; }
  s = wave_sum64(s);
  float mu = s * (1.f / 512.f);
  float vs = 0.f;
#pragma unroll
  for (int i = 0; i < 8; i++) { float d = v[i] - mu; vs = fmaf(d, d, vs); }
  vs = wave_sum64(vs);
  float rstd = rsqrtf(vs * (1.f / 512.f) + 1e-5f);
  float* op = out + (size_t)row * 512;
  unsigned short* ob = out_bf + (size_t)row * 512;
#pragma unroll
  for (int i = 0; i < 8; i++) {
    float y = (v[i] - mu) * rstd * g[lane + 64 * i] + b[lane + 64 * i];
    op[lane + 64 * i] = y;
    ob[lane + 64 * i] = f2bf(y);
  }
}

// ---------------- multi-job f32 -> bf16 cast (one launch per batch) ----------------
struct CastJobs {
  const float* src[6];
  unsigned short* dst[6];
  int n4[6];
  int njobs;
};

__global__ void cast_multi(CastJobs J)
{
  for (int j = 0; j < J.njobs; j++) {
    const float4* s = (const float4*)J.src[j];
    ushort4* d = (ushort4*)J.dst[j];
    int n = J.n4[j];
    for (int i = blockIdx.x * 256 + threadIdx.x; i < n; i += gridDim.x * 256) {
      float4 v = s[i];
      ushort4 u;
      u.x = f2bf(v.x); u.y = f2bf(v.y); u.z = f2bf(v.z); u.w = f2bf(v.w);
      d[i] = u;
    }
  }
}

__global__ void init_h(const float* __restrict__ in, float* __restrict__ hf,
                       unsigned short* __restrict__ hb, int n4)
{
  int i = blockIdx.x * 256 + threadIdx.x;
  if (i < n4) {
    float4 v = ((const float4*)in)[i];
    ((float4*)hf)[i] = v;
    ushort4 u;
    u.x = f2bf(v.x); u.y = f2bf(v.y); u.z = f2bf(v.z); u.w = f2bf(v.w);
    ((ushort4*)hb)[i] = u;
  }
}

// ---------------- A[t] = sum_l Gv*Gu*Ww + bw ----------------
__global__ __launch_bounds__(128) void gate_dot(
    const float* __restrict__ Gv, const float* __restrict__ Gu, int ld,
    const float* __restrict__ Ww, const float* __restrict__ bw,
    float* __restrict__ A)
{
  const int t = blockIdx.x, l = threadIdx.x;
  float v = Gv[(size_t)t * ld + l] * Gu[(size_t)t * ld + l] * Ww[l];
  v = wave_sum64(v);
  __shared__ float red[2];
  if ((l & 63) == 0) red[l >> 6] = v;
  __syncthreads();
  if (l == 0) A[t] = red[0] + red[1] + bw[0];
}

// ------- contiguous-segment softmax + weighted pooled sum (D=512) -------
__global__ __launch_bounds__(256) void seg_pool(
    const float* __restrict__ A, const float* __restrict__ X,
    float* __restrict__ w_out, float* __restrict__ out, int seg_len)
{
  const int s = blockIdx.x, tid = threadIdx.x;
  __shared__ float ws[16];
  if (tid < 64) {
    float a = (tid < seg_len) ? A[s * seg_len + tid] : -1e30f;
    float mx = a;
#pragma unroll
    for (int o = 1; o < 16; o <<= 1) mx = fmaxf(mx, __shfl_xor(mx, o));
    float e = (tid < seg_len) ? expf(a - mx) : 0.f;
    float se = e;
#pragma unroll
    for (int o = 1; o < 16; o <<= 1) se += __shfl_xor(se, o);
    if (tid < seg_len) {
      float w = e / se;
      ws[tid] = w;
      w_out[s * seg_len + tid] = w;
    }
  }
  __syncthreads();
  for (int d = tid; d < 512; d += 256) {
    float acc = 0.f;
    for (int i = 0; i < seg_len; i++)
      acc = fmaf(ws[i], X[(size_t)(s * seg_len + i) * 512 + d], acc);
    out[(size_t)s * 512 + d] = acc;
  }
}

// ======================= CNN head (channels-last [n][L][C=128]) =======================

__global__ void conv1_bnT(
    const float* __restrict__ x, const float* __restrict__ K4,
    const float* __restrict__ bias, const float* __restrict__ g,
    const float* __restrict__ bb, unsigned short* __restrict__ y)
{
  int idx = blockIdx.x * 256 + threadIdx.x;   // (n*512+i)*128+o
  int o = idx & 127, i = (idx >> 7) & 511, n = idx >> 16;
  const float* xp = x + n * 512;
  float acc = bias[o];
#pragma unroll
  for (int k = 0; k < 4; k++) {
    int p = i + k - 1;
    float xv = (p >= 0 && p < 512) ? xp[p] : 0.f;
    acc = fmaf(xv, K4[o * 4 + k], acc);
  }
  float sc = g[o] * rsqrtf(1.f + 1e-5f);
  y[idx] = f2bf(fmaxf(fmaf(acc, sc, bb[o]), 0.f));
}

__global__ void reorder_w(const float* __restrict__ Kc, unsigned short* __restrict__ Wr,
                          int KS, int total)
{
  int idx = blockIdx.x * 256 + threadIdx.x;
  if (idx < total) {
    int c = idx & 127;
    int kk = (idx >> 7) % KS;
    int o = idx / (128 * KS);
    Wr[idx] = f2bf(Kc[(o * 128 + c) * KS + kk]);
  }
}

template<int KS, int PAD, int LEN, int OUTF>
__global__ __launch_bounds__(256) void convT_mfma(
    const unsigned short* __restrict__ X, const unsigned short* __restrict__ Wr,
    const float* __restrict__ bias, const float* __restrict__ g,
    const float* __restrict__ bb,
    unsigned short* __restrict__ Yb, float* __restrict__ Yf)
{
  constexpr int ROWS = 64 + KS - 1;
  __shared__ __align__(16) unsigned short XT[ROWS * 128];
  const int tid = threadIdx.x;
  const int w = tid >> 6, lane = tid & 63;
  const int l15 = lane & 15, l4 = lane >> 4;
  const int i0 = (blockIdx.x >> 1) * 64;
  const int o0 = (blockIdx.x & 1) * 64;
  const int n = blockIdx.y;

  {
    const int c = (tid & 15) * 8;
    for (int r = tid >> 4; r < ROWS; r += 16) {
      int gi = i0 - PAD + r;
      bf16x8 v = {};
      if (gi >= 0 && gi < LEN)
        v = *(const bf16x8*)&X[((size_t)n * LEN + gi) * 128 + c];
      int byte = r * 256 + c * 2;
      *(bf16x8*)((char*)XT + swz256(byte)) = v;
    }
  }
  __syncthreads();

  f32x4 acc[4] = {};
#pragma unroll
  for (int kk = 0; kk < KS; kk++) {
#pragma unroll
    for (int cc = 0; cc < 4; cc++) {
      int r = w * 16 + l15 + kk;
      int byte = r * 256 + cc * 64 + l4 * 16;
      bf16x8 a = *(const bf16x8*)((const char*)XT + swz256(byte));
      bf16x8 bfr[4];
#pragma unroll
      for (int nb = 0; nb < 4; nb++)
        bfr[nb] = *(const bf16x8*)&Wr[(size_t)(o0 + nb * 16 + l15) * (KS * 128) +
                                      kk * 128 + cc * 32 + l4 * 8];
#pragma unroll
      for (int nb = 0; nb < 4; nb++)
        acc[nb] = __builtin_amdgcn_mfma_f32_16x16x32_bf16(a, bfr[nb], acc[nb], 0, 0, 0);
    }
  }

#pragma unroll
  for (int nb = 0; nb < 4; nb++) {
    int o = o0 + nb * 16 + l15;
    float sc = g[o] * rsqrtf(1.f + 1e-5f);
    float bs = bias[o], bo_ = bb[o];
#pragma unroll
    for (int rr = 0; rr < 4; rr++) {
      int i = i0 + w * 16 + l4 * 4 + rr;
      float v = fmaxf(fmaf(acc[nb][rr] + bs, sc, bo_), 0.f);
      size_t oidx = ((size_t)n * LEN + i) * 128 + o;
      if (OUTF) Yf[oidx] = v;
      else Yb[oidx] = f2bf(v);
    }
  }
}

__global__ void avgpool2_bf(const unsigned short* __restrict__ x,
                            unsigned short* __restrict__ y, int nI, int nTot4)
{
  int j = blockIdx.x * 256 + threadIdx.x;
  if (j >= nTot4) return;
  int cq = j & 31;
  int i = (j >> 5) % nI;
  int n = j / (nI * 32);
  const ushort4* a = (const ushort4*)&x[(((size_t)n * nI + i) * 2) * 128 + cq * 4];
  const ushort4* b = (const ushort4*)&x[(((size_t)n * nI + i) * 2 + 1) * 128 + cq * 4];
  ushort4 ua = *a, ub = *b;
  ushort4 r;
  r.x = f2bf(0.5f * (bf2f(ua.x) + bf2f(ub.x)));
  r.y = f2bf(0.5f * (bf2f(ua.y) + bf2f(ub.y)));
  r.z = f2bf(0.5f * (bf2f(ua.z) + bf2f(ub.z)));
  r.w = f2bf(0.5f * (bf2f(ua.w) + bf2f(ub.w)));
  ((ushort4*)y)[j] = r;
}

__global__ void pool3_transpose(const float* __restrict__ x, float* __restrict__ y)
{
  int j = blockIdx.x * 256 + threadIdx.x;   // n*16384 + c*128 + i
  if (j >= 524288) return;
  int i = j & 127, c = (j >> 7) & 127, n = j >> 14;
  const float* b = x + ((size_t)n * 256 + 2 * i) * 128 + c;
  y[j] = 0.5f * (b[0] + b[128]);
}

__global__ __launch_bounds__(256) void fc1_kernel(
    const float* __restrict__ x, const float* __restrict__ W,
    const float* __restrict__ bias, const float* __restrict__ g,
    const float* __restrict__ bb, float* __restrict__ y)
{
  int o = blockIdx.x & 255, n = blockIdx.x >> 8;
  const float* xp = x + (size_t)n * 16384;
  const float* wp = W + (size_t)o * 16384;
  float s = 0.f;
  for (int j = threadIdx.x * 4; j < 16384; j += 1024) {
    float4 a = *(const float4*)(xp + j);
    float4 b = *(const float4*)(wp + j);
    s = fmaf(a.x, b.x, s); s = fmaf(a.y, b.y, s);
    s = fmaf(a.z, b.z, s); s = fmaf(a.w, b.w, s);
  }
  s = wave_sum64(s);
  __shared__ float red[4];
  if ((threadIdx.x & 63) == 0) red[threadIdx.x >> 6] = s;
  __syncthreads();
  if (threadIdx.x == 0) {
    float v = red[0] + red[1] + red[2] + red[3] + bias[o];
    v = fmaxf(v, 0.f);
    y[n * 256 + o] = fmaf(v, g[o] * rsqrtf(1.f + 1e-5f), bb[o]);
  }
}

__global__ __launch_bounds__(256) void fc2_kernel(
    const float* __restrict__ x, const float* __restrict__ W,
    const float* __restrict__ bias, const float* __restrict__ g,
    const float* __restrict__ bb, float* __restrict__ y)
{
  int o = blockIdx.x & 127, n = blockIdx.x >> 7;
  float s = x[n * 256 + threadIdx.x] * W[o * 256 + threadIdx.x];
  s = wave_sum64(s);
  __shared__ float red[4];
  if ((threadIdx.x & 63) == 0) red[threadIdx.x >> 6] = s;
  __syncthreads();
  if (threadIdx.x == 0) {
    float v = red[0] + red[1] + red[2] + red[3] + bias[o];
    v = fmaxf(v, 0.f);
    y[n * 128 + o] = fmaf(v, g[o] * rsqrtf(1.f + 1e-5f), bb[o]);
  }
}

__global__ __launch_bounds__(64) void fc3_kernel(
    const float* __restrict__ x, const float* __restrict__ W,
    const float* __restrict__ bias, float* __restrict__ out)
{
  int n = threadIdx.x;
  if (n < 32) {
    float s = bias[0];
    for (int k = 0; k < 128; k++) s = fmaf(x[n * 128 + k], W[k], s);
    float p = 1.f / (1.f + expf(-s));
    out[n] = p;
    out[32 + n] = (p >= 0.5f) ? 1.f : 0.f;
  }
}

extern "C" void kernel_launch(void* const* d_in, const int* in_sizes, int n_in,
                              void* d_out, int out_size, void* d_ws, size_t ws_size,
                              hipStream_t stream)
{
  const float* datas = (const float*)d_in[0];
  const float* Wqkv = (const float*)d_in[6];
  const float* bqkv = (const float*)d_in[7];
  const float* Wo   = (const float*)d_in[8];
  const float* bo   = (const float*)d_in[9];
  const float* ln1g = (const float*)d_in[10];
  const float* ln1b = (const float*)d_in[11];
  const float* W1   = (const float*)d_in[12];
  const float* b1   = (const float*)d_in[13];
  const float* W2   = (const float*)d_in[14];
  const float* b2   = (const float*)d_in[15];
  const float* ln2g = (const float*)d_in[16];
  const float* ln2b = (const float*)d_in[17];
  const float* Wv1  = (const float*)d_in[18];
  const float* bv1  = (const float*)d_in[19];
  const float* Wu1  = (const float*)d_in[20];
  const float* bu1  = (const float*)d_in[21];
  const float* Ww1  = (const float*)d_in[22];
  const float* bw1  = (const float*)d_in[23];
  const float* Wv2  = (const float*)d_in[24];
  const float* bv2  = (const float*)d_in[25];
  const float* Wu2  = (const float*)d_in[26];
  const float* bu2  = (const float*)d_in[27];
  const float* Ww2  = (const float*)d_in[28];
  const float* bw2  = (const float*)d_in[29];
  const float* Kc1  = (const float*)d_in[30];
  const float* bc1  = (const float*)d_in[31];
  const float* gc1  = (const float*)d_in[32];
  const float* bb1  = (const float*)d_in[33];
  const float* Kc2  = (const float*)d_in[34];
  const float* bc2  = (const float*)d_in[35];
  const float* gc2  = (const float*)d_in[36];
  const float* bb2  = (const float*)d_in[37];
  const float* Kc3  = (const float*)d_in[38];
  const float* bc3  = (const float*)d_in[39];
  const float* gc3  = (const float*)d_in[40];
  const float* bb3  = (const float*)d_in[41];
  const float* Wf1  = (const float*)d_in[42];
  const float* bf1  = (const float*)d_in[43];
  const float* g4   = (const float*)d_in[44];
  const float* b4   = (const float*)d_in[45];
  const float* Wf2  = (const float*)d_in[46];
  const float* bf2  = (const float*)d_in[47];
  const float* g5   = (const float*)d_in[48];
  const float* b5   = (const float*)d_in[49];
  const float* Wf3  = (const float*)d_in[50];
  const float* bf3  = (const float*)d_in[51];

  float* ws = (float*)d_ws;
  float* h_f32 = ws;                              // 2,097,152 f
  float* R2f   = ws + 2097152;                    // 6,291,456 f
  unsigned short* h_bf = (unsigned short*)(ws + 8388608);   // 2,097,152 ush
  unsigned short* wbuf = (unsigned short*)(ws + 9437184);   // 3,473,408 ush
  float* biasG = ws + 11173888;                   // 256 f
  unsigned short* VTg = (unsigned short*)(ws + 11174144);   // 2,097,152 ush (V^T [512][4096])

  unsigned short* qkv_bf = (unsigned short*)R2f;
  unsigned short* O_bf   = (unsigned short*)(R2f + 3145728);
  unsigned short* ff1_bf = (unsigned short*)R2f;
  float* projf = R2f + 4194304;

  unsigned short* WqkvB = wbuf;                 // 786,432 (per-layer reuse)
  unsigned short* WoB   = wbuf + 786432;        // 262,144
  unsigned short* W1B   = wbuf + 1048576;       // 1,048,576
  unsigned short* W2B   = wbuf + 2097152;       // 1,048,576
  unsigned short* WvuB  = wbuf + 3145728;       // 131,072 (persistent tail)
  unsigned short* Wr2B  = wbuf + 3276800;       // 81,920
  unsigned short* Wr3B  = wbuf + 3358720;       // 114,688

  float* out_f = (float*)d_out;

  init_h<<<2048, 256, 0, stream>>>(datas, h_f32, h_bf, 524288);
  reorder_w<<<320, 256, 0, stream>>>(Kc2, Wr2B, 5, 81920);
  reorder_w<<<448, 256, 0, stream>>>(Kc3, Wr3B, 7, 114688);
  hipMemcpyAsync(biasG, bv1, 128 * sizeof(float), hipMemcpyDeviceToDevice, stream);
  hipMemcpyAsync(biasG + 128, bu1, 128 * sizeof(float), hipMemcpyDeviceToDevice, stream);

  for (int l = 0; l < 2; l++) {
    CastJobs J{};
    J.src[0] = Wqkv + (size_t)l * 786432;  J.dst[0] = WqkvB; J.n4[0] = 196608;
    J.src[1] = Wo   + (size_t)l * 262144;  J.dst[1] = WoB;   J.n4[1] = 65536;
    J.src[2] = W1   + (size_t)l * 1048576; J.dst[2] = W1B;   J.n4[2] = 262144;
    J.src[3] = W2   + (size_t)l * 1048576; J.dst[3] = W2B;   J.n4[3] = 262144;
    J.njobs = 4;
    if (l == 0) {
      J.src[4] = Wv1; J.dst[4] = WvuB;         J.n4[4] = 16384;
      J.src[5] = Wu1; J.dst[5] = WvuB + 65536; J.n4[5] = 16384;
      J.njobs = 6;
    }
    cast_multi<<<512, 256, 0, stream>>>(J);

    // qkv: Q,K -> qkv_bf [t][1536]; V -> VTg [h*64+d][t]
    mgemm<0, 1, 1><<<dim3(12, 32), 256, 0, stream>>>(
        h_bf, WqkvB, bqkv + (size_t)l * 1536, nullptr, qkv_bf, VTg, 4096, 1536, 512);
    attn_mfma<<<dim3(32, 8), 256, 0, stream>>>(qkv_bf, VTg, O_bf);
    mgemm<0, 0, 0><<<dim3(4, 32), 256, 0, stream>>>(
        O_bf, WoB, bo + (size_t)l * 512, projf, nullptr, nullptr, 4096, 512, 512);
    residual_ln<<<4096, 64, 0, stream>>>(projf, h_f32, ln1g + l * 512, ln1b + l * 512,
                                         h_f32, h_bf);
    mgemm<1, 1, 0><<<dim3(16, 32), 256, 0, stream>>>(
        h_bf, W1B, b1 + (size_t)l * 2048, nullptr, ff1_bf, nullptr, 4096, 2048, 512);
    mgemm<0, 0, 0><<<dim3(4, 32), 256, 0, stream>>>(
        ff1_bf, W2B, b2 + (size_t)l * 512, projf, nullptr, nullptr, 4096, 512, 2048);
    residual_ln<<<4096, 64, 0, stream>>>(projf, h_f32, ln2g + l * 512, ln2b + l * 512,
                                         h_f32, h_bf);
  }

  // ---- gated pooling (stage 1: fused tanh/sigmoid GEMM, N=256) ----
  float* G    = R2f;              // 4096 x 256
  float* A1   = R2f + 1048576;
  float* out1 = R2f + 1052672;
  float* Gv2  = R2f + 1183744;
  float* Gu2  = R2f + 1216512;
  float* A2   = R2f + 1249280;
  float* out2 = R2f + 1249536;

  mgemm<4, 0, 0><<<dim3(2, 32), 256, 0, stream>>>(
      h_bf, WvuB, biasG, G, nullptr, nullptr, 4096, 256, 512);
  gate_dot<<<4096, 128, 0, stream>>>(G, G + 128, 256, Ww1, bw1, A1);
  seg_pool<<<256, 256, 0, stream>>>(A1, h_f32, out_f + 64, out1, 16);

  gemm_bias<2><<<dim3(2, 4), 256, 0, stream>>>(out1, Wv2, bv2, Gv2, 256, 128, 512);
  gemm_bias<3><<<dim3(2, 4), 256, 0, stream>>>(out1, Wu2, bu2, Gu2, 256, 128, 512);
  gate_dot<<<256, 128, 0, stream>>>(Gv2, Gu2, 128, Ww2, bw2, A2);
  seg_pool<<<32, 256, 0, stream>>>(A2, out1, out_f + 4160, out2, 8);

  // ---- CNN head, channels-last ----
  unsigned short* c1T = (unsigned short*)(R2f + 1310720);  // 2,097,152 ush
  unsigned short* c2T = (unsigned short*)(R2f + 2359296);  // 2,097,152 ush
  unsigned short* p2T = (unsigned short*)(R2f + 3407872);  // 1,048,576 ush
  float* c3T = R2f + 3932160;                              // 1,048,576 f
  float* p3R = R2f + 4980736;                              // 524,288 f
  float* f1  = R2f + 5505024;
  float* f2  = R2f + 5513216;

  conv1_bnT<<<8192, 256, 0, stream>>>(out2, Kc1, bc1, gc1, bb1, c1T);
  convT_mfma<5, 2, 512, 0><<<dim3(16, 32), 256, 0, stream>>>(
      c1T, Wr2B, bc2, gc2, bb2, c2T, nullptr);
  avgpool2_bf<<<1024, 256, 0, stream>>>(c2T, p2T, 256, 262144);
  convT_mfma<7, 3, 256, 1><<<dim3(8, 32), 256, 0, stream>>>(
      p2T, Wr3B, bc3, gc3, bb3, nullptr, c3T);
  pool3_transpose<<<2048, 256, 0, stream>>>(c3T, p3R);
  fc1_kernel<<<8192, 256, 0, stream>>>(p3R, Wf1, bf1, g4, b4, f1);
  fc2_kernel<<<4096, 256, 0, stream>>>(f1, Wf2, bf2, g5, b5, f2);
  fc3_kernel<<<1, 64, 0, stream>>>(f2, Wf3, bf3, out_f);
}

// Round 11
// 650.175 us; speedup vs baseline: 1.0212x; 1.0212x over previous
//
#include <hip/hip_runtime.h>
#include <math.h>

// T=4096, M=512, NH=8, HD=64, FF=2048, NL=2, NI=256 (16 tok/seg), NO=32 (8 seg/outer)

typedef float f32x4 __attribute__((ext_vector_type(4)));
typedef __bf16 bf16x8 __attribute__((ext_vector_type(8)));

__device__ __forceinline__ unsigned short f2bf(float x) {
  unsigned int u = __builtin_bit_cast(unsigned int, x);
  u += 0x7FFFu + ((u >> 16) & 1u);
  return (unsigned short)(u >> 16);
}
__device__ __forceinline__ float bf2f(unsigned short u) {
  unsigned int x = ((unsigned int)u) << 16;
  return __builtin_bit_cast(float, x);
}
// pack two f32 -> two bf16 (RTNE) in one instruction
__device__ __forceinline__ unsigned int pk_bf16(float a, float b) {
  unsigned int r;
  asm("v_cvt_pk_bf16_f32 %0, %1, %2" : "=v"(r) : "v"(a), "v"(b));
  return r;
}

// async global -> LDS, 16 bytes/lane. LDS dest = wave-uniform base + lane*16
// (CK-style addrspace casts: AS1 via 64-bit VA, AS3 via low-32-bit LDS offset).
__device__ __forceinline__ void gload16(const unsigned short* g, unsigned short* l) {
  __builtin_amdgcn_global_load_lds(
      (const __attribute__((address_space(1))) unsigned int*)(uintptr_t)g,
      (__attribute__((address_space(3))) unsigned int*)(unsigned int)(uintptr_t)l,
      16, 0, 0);
}

__device__ __forceinline__ float wave_sum64(float v) {
#pragma unroll
  for (int o = 32; o > 0; o >>= 1) v += __shfl_xor(v, o);
  return v;
}

// XOR swizzle for LDS tiles with 128-byte rows (64 bf16/row).
__device__ __forceinline__ int swz(int byte) {
  return byte ^ (((byte >> 7) & 7) << 4);
}
// XOR swizzle for LDS tiles with 256-byte rows (128 bf16/row).
__device__ __forceinline__ int swz256(int byte) {
  return byte ^ (((byte >> 8) & 7) << 4);
}

// ============ bf16 MFMA GEMM: C[M,N] = act(A[M,K] @ B[N,K]^T + bias) ============
// ACT: 0 none, 1 relu, 2 tanh, 3 sigmoid, 4 col<128?tanh:sigmoid (fused gate)
// VSPLIT: cols >= 1024 go to VT[col-1024][row] (bf16, packed 4-row stores).
// Staging: direct global_load_lds (width 16) into LINEAR [128][64] LDS tiles
// (m97/m151 structure). MFMA fragment values & order identical to the
// reg-staged version -> bit-exact outputs.
template<int ACT, int OUTBF, int VSPLIT>
__global__ __launch_bounds__(256) void mgemm(
    const unsigned short* __restrict__ A, const unsigned short* __restrict__ B,
    const float* __restrict__ bias, float* __restrict__ Cf,
    unsigned short* __restrict__ Cb, unsigned short* __restrict__ VT,
    int M, int N, int K)
{
  __shared__ __align__(1024) unsigned short As[128 * 64];
  __shared__ __align__(1024) unsigned short Bs[128 * 64];
  const int tid = threadIdx.x;
  const int wid = tid >> 6, lane = tid & 63;
  const int wm = wid >> 1, wn = wid & 1;
  const int l15 = lane & 15, l4 = lane >> 4;
  const int m0 = blockIdx.y * 128, n0 = blockIdx.x * 128;
  const int srow8 = lane >> 3;        // row within 8-row chunk
  const int scol  = (lane & 7) * 8;   // bf16 col within row

  f32x4 acc[4][4] = {};

  for (int k0 = 0; k0 < K; k0 += 64) {
    __syncthreads();   // all waves done reading previous LDS tile
#pragma unroll
    for (int t = 0; t < 4; t++) {
      int chunk = wid * 4 + t;            // 16 chunks of 8 rows x 64 cols
      int row = chunk * 8 + srow8;
      gload16(&A[(size_t)(m0 + row) * K + k0 + scol], &As[chunk * 512]);
      gload16(&B[(size_t)(n0 + row) * K + k0 + scol], &Bs[chunk * 512]);
    }
    __syncthreads();   // compiler drains vmcnt before barrier; LDS ready
#pragma unroll
    for (int kc = 0; kc < 2; kc++) {
      bf16x8 af[4], bf_[4];
#pragma unroll
      for (int i = 0; i < 4; i++) {
        int byteA = (wm * 64 + i * 16 + l15) * 128 + kc * 64 + l4 * 16;
        af[i] = *(const bf16x8*)((const char*)As + byteA);
        int byteB = (wn * 64 + i * 16 + l15) * 128 + kc * 64 + l4 * 16;
        bf_[i] = *(const bf16x8*)((const char*)Bs + byteB);
      }
#pragma unroll
      for (int i = 0; i < 4; i++)
#pragma unroll
        for (int j = 0; j < 4; j++)
          acc[i][j] = __builtin_amdgcn_mfma_f32_16x16x32_bf16(af[i], bf_[j], acc[i][j], 0, 0, 0);
    }
  }
#pragma unroll
  for (int i = 0; i < 4; i++) {
#pragma unroll
    for (int j = 0; j < 4; j++) {
      int col = n0 + wn * 64 + j * 16 + l15;
      float bv = bias[col];
      if (VSPLIT && col >= 1024) {
        float x0 = acc[i][j][0] + bv, x1 = acc[i][j][1] + bv;
        float x2 = acc[i][j][2] + bv, x3 = acc[i][j][3] + bv;
        uint2 pv;
        pv.x = pk_bf16(x0, x1);
        pv.y = pk_bf16(x2, x3);
        int row0 = m0 + wm * 64 + i * 16 + l4 * 4;
        *(uint2*)&VT[(size_t)(col - 1024) * 4096 + row0] = pv;
      } else {
#pragma unroll
        for (int r = 0; r < 4; r++) {
          int row = m0 + wm * 64 + i * 16 + l4 * 4 + r;
          float x = acc[i][j][r] + bv;
          if (ACT == 1) x = fmaxf(x, 0.f);
          if (ACT == 2) x = tanhf(x);
          if (ACT == 3) x = 1.f / (1.f + expf(-x));
          if (ACT == 4) x = (col < 128) ? tanhf(x) : (1.f / (1.f + expf(-x)));
          if (OUTBF) Cb[(size_t)row * N + col] = f2bf(x);
          else       Cf[(size_t)row * N + col] = x;
        }
      }
    }
  }
}

// ============ MFMA flash attention (round-9 version, verbatim) ============
// Swapped operands (lane-local softmax), HBM-pretransposed V, bit-exact prefetch.
__global__ __launch_bounds__(256) void attn_mfma(
    const unsigned short* __restrict__ qkv, const unsigned short* __restrict__ VT,
    unsigned short* __restrict__ O)
{
  __shared__ __align__(16) unsigned short Ks[64 * 64];   // [k][d]   swizzled
  __shared__ __align__(16) unsigned short VTs[64 * 64];  // [d][k]   swizzled
  __shared__ __align__(16) unsigned short Ps[64 * 64];   // [q][k]   swizzled
  const int tid = threadIdx.x;
  const int w = tid >> 6, lane = tid & 63;
  const int l15 = lane & 15, l4 = lane >> 4;
  const int h = blockIdx.y, qt = blockIdx.x;
  const float C = 0.18033688011112042f;   // 0.125 * log2(e)

  // Q fragment (B operand for S^T: col = q = l15)
  bf16x8 qf[2];
#pragma unroll
  for (int kc = 0; kc < 2; kc++)
    qf[kc] = *(const bf16x8*)&qkv[(size_t)(qt * 64 + w * 16 + l15) * 1536 + h * 64 + kc * 32 + l4 * 8];

  f32x4 oaccT[4] = {};
  float m = -1e30f, l = 0.f;

  const int sr = tid >> 3;
  const int sc = (tid & 7) * 8;
  // V^T staging: thread -> (d row, 16-k chunk)
  const int vd = tid >> 2;            // 0..63
  const int vk0 = (tid & 3) * 16;     // 0,16,32,48

  const unsigned short* kp0 = qkv + (size_t)sr * 1536 + 512 + h * 64 + sc;
  const unsigned short* kp1 = kp0 + 32 * 1536;
  const unsigned short* vp = VT + (size_t)(h * 64 + vd) * 4096 + vk0;

  bf16x8 rk0 = *(const bf16x8*)kp0;
  bf16x8 rk1 = *(const bf16x8*)kp1;
  bf16x8 rv0 = *(const bf16x8*)vp;
  bf16x8 rv1 = *(const bf16x8*)(vp + 8);

  for (int kt = 0; kt < 64; kt++) {
    __syncthreads();   // previous tile fully consumed
    {
      int b0 = sr * 128 + sc * 2;
      *(bf16x8*)((char*)Ks + swz(b0)) = rk0;
      int b1 = (sr + 32) * 128 + sc * 2;
      *(bf16x8*)((char*)Ks + swz(b1)) = rk1;
      int vb0 = vd * 128 + vk0 * 2;
      *(bf16x8*)((char*)VTs + swz(vb0)) = rv0;
      *(bf16x8*)((char*)VTs + swz(vb0 + 16)) = rv1;
    }
    __syncthreads();   // LDS ready
    if (kt < 63) {     // prefetch next tile (bit-exact; hides HBM latency)
      kp0 += 64 * 1536; kp1 += 64 * 1536; vp += 64;
      rk0 = *(const bf16x8*)kp0;
      rk1 = *(const bf16x8*)kp1;
      rv0 = *(const bf16x8*)vp;
      rv1 = *(const bf16x8*)(vp + 8);
    }

    // S^T = mfma(A=K, B=Q): lane holds st[nb][r] = S[k=nb*16+l4*4+r][q=w*16+l15]
    f32x4 st[4] = {};
    __builtin_amdgcn_s_setprio(1);
#pragma unroll
    for (int kc = 0; kc < 2; kc++) {
#pragma unroll
      for (int nb = 0; nb < 4; nb++) {
        int byte = (nb * 16 + l15) * 128 + kc * 64 + l4 * 16;
        bf16x8 kf = *(const bf16x8*)((const char*)Ks + swz(byte));
        st[nb] = __builtin_amdgcn_mfma_f32_16x16x32_bf16(kf, qf[kc], st[nb], 0, 0, 0);
      }
    }
    __builtin_amdgcn_s_setprio(0);

    // lane-local online softmax (always rescale — round-3/8 exact numerics)
    float tm = -1e30f;
#pragma unroll
    for (int nb = 0; nb < 4; nb++)
#pragma unroll
      for (int r = 0; r < 4; r++) tm = fmaxf(tm, st[nb][r]);
    tm = fmaxf(tm, __shfl_xor(tm, 16));
    tm = fmaxf(tm, __shfl_xor(tm, 32));
    float mn = fmaxf(m, tm);
    float alpha = exp2f((m - mn) * C);
    float e[4][4];
    float ps = 0.f;
#pragma unroll
    for (int nb = 0; nb < 4; nb++)
#pragma unroll
      for (int r = 0; r < 4; r++) {
        e[nb][r] = exp2f((st[nb][r] - mn) * C);
        ps += e[nb][r];
      }
    ps += __shfl_xor(ps, 16);
    ps += __shfl_xor(ps, 32);
    l = l * alpha + ps;
    m = mn;
#pragma unroll
    for (int nb = 0; nb < 4; nb++) oaccT[nb] *= alpha;

    // P rows -> Ps[q][k] (lane writes its own q-row; wave-local, no barrier)
#pragma unroll
    for (int nb = 0; nb < 4; nb++) {
      uint2 pr;
      pr.x = pk_bf16(e[nb][0], e[nb][1]);
      pr.y = pk_bf16(e[nb][2], e[nb][3]);
      int byte = (w * 16 + l15) * 128 + (nb * 16 + l4 * 4) * 2;
      *(uint2*)((char*)Ps + swz(byte)) = pr;
    }

    // O^T += mfma(A=V^T, B=P)
#pragma unroll
    for (int kc = 0; kc < 2; kc++) {
      int bp = (w * 16 + l15) * 128 + kc * 64 + l4 * 16;
      bf16x8 pb = *(const bf16x8*)((const char*)Ps + swz(bp));
      __builtin_amdgcn_s_setprio(1);
#pragma unroll
      for (int nb = 0; nb < 4; nb++) {
        int bv = (nb * 16 + l15) * 128 + kc * 64 + l4 * 16;
        bf16x8 vf = *(const bf16x8*)((const char*)VTs + swz(bv));
        oaccT[nb] = __builtin_amdgcn_mfma_f32_16x16x32_bf16(vf, pb, oaccT[nb], 0, 0, 0);
      }
      __builtin_amdgcn_s_setprio(0);
    }
  }

  // epilogue: in-lane 1/l, packed 8-byte stores
  float linv = 1.f / l;
  int row = qt * 64 + w * 16 + l15;
#pragma unroll
  for (int nb = 0; nb < 4; nb++) {
    uint2 ov;
    ov.x = pk_bf16(oaccT[nb][0] * linv, oaccT[nb][1] * linv);
    ov.y = pk_bf16(oaccT[nb][2] * linv, oaccT[nb][3] * linv);
    int col = h * 64 + nb * 16 + l4 * 4;
    *(uint2*)&O[(size_t)row * 512 + col] = ov;
  }
}

// ---------------- fp32 GEMM (tiny stage-2 gating) ----------------
template<int ACT>
__global__ __launch_bounds__(256) void gemm_bias(
    const float* __restrict__ A, const float* __restrict__ B,
    const float* __restrict__ bias, float* __restrict__ C,
    int M, int N, int K)
{
  __shared__ float As[16][68];
  __shared__ float Bs[16][68];
  const int tid = threadIdx.x;
  const int tx = tid & 15, ty = tid >> 4;
  const int m0 = blockIdx.y * 64, n0 = blockIdx.x * 64;
  const int lr = tid >> 2;
  const int lk = (tid & 3) * 4;
  float acc[4][4] = {};
  for (int k0 = 0; k0 < K; k0 += 16) {
    __syncthreads();
    float4 av = *(const float4*)&A[(size_t)(m0 + lr) * K + k0 + lk];
    float4 bv = *(const float4*)&B[(size_t)(n0 + lr) * K + k0 + lk];
    As[lk + 0][lr] = av.x; As[lk + 1][lr] = av.y; As[lk + 2][lr] = av.z; As[lk + 3][lr] = av.w;
    Bs[lk + 0][lr] = bv.x; Bs[lk + 1][lr] = bv.y; Bs[lk + 2][lr] = bv.z; Bs[lk + 3][lr] = bv.w;
    __syncthreads();
#pragma unroll
    for (int k = 0; k < 16; k++) {
      float a[4], b[4];
#pragma unroll
      for (int i = 0; i < 4; i++) a[i] = As[k][ty * 4 + i];
#pragma unroll
      for (int j = 0; j < 4; j++) b[j] = Bs[k][tx * 4 + j];
#pragma unroll
      for (int i = 0; i < 4; i++)
#pragma unroll
        for (int j = 0; j < 4; j++)
          acc[i][j] = fmaf(a[i], b[j], acc[i][j]);
    }
  }
#pragma unroll
  for (int i = 0; i < 4; i++)
#pragma unroll
    for (int j = 0; j < 4; j++) {
      float x = acc[i][j] + bias[n0 + tx * 4 + j];
      if (ACT == 1) x = fmaxf(x, 0.f);
      if (ACT == 2) x = tanhf(x);
      if (ACT == 3) x = 1.f / (1.f + expf(-x));
      C[(size_t)(m0 + ty * 4 + i) * N + n0 + tx * 4 + j] = x;
    }
}

// ---------------- LayerNorm(x + res), writes f32 + bf16 ----------------
__global__ __launch_bounds__(64) void residual_ln(
    const float* __restrict__ x, const float* __restrict__ res,
    const float* __restrict__ g, const float* __restrict__ b,
    float* __restrict__ out, unsigned short* __restrict__ out_bf)
{
  const int row = blockIdx.x, lane = threadIdx.x;
  const float* xp = x + (size_t)row * 512;
  const float* rp = res + (size_t)row * 512;
  float v[8];
  float s = 0.f;
#pragma unroll
  for (int i = 0; i < 8; i++) { v[i] = xp[lane + 64 * i] + rp[lane + 64 * i]; s += v[i]; }
  s = wave_sum64(s);
  float mu = s * (1.f / 512.f);
  float vs = 0.f;
#pragma unroll
  for (int i = 0; i < 8; i++) { float d = v[i] - mu; vs = fmaf(d, d, vs); }
  vs = wave_sum64(vs);
  float rstd = rsqrtf(vs * (1.f / 512.f) + 1e-5f);
  float* op = out + (size_t)row * 512;
  unsigned short* ob = out_bf + (size_t)row * 512;
#pragma unroll
  for (int i = 0; i < 8; i++) {
    float y = (v[i] - mu) * rstd * g[lane + 64 * i] + b[lane + 64 * i];
    op[lane + 64 * i] = y;
    ob[lane + 64 * i] = f2bf(y);
  }
}

// ---------------- multi-job f32 -> bf16 cast (one launch per batch) ----------------
struct CastJobs {
  const float* src[6];
  unsigned short* dst[6];
  int n4[6];
  int njobs;
};

__global__ void cast_multi(CastJobs J)
{
  for (int j = 0; j < J.njobs; j++) {
    const float4* s = (const float4*)J.src[j];
    ushort4* d = (ushort4*)J.dst[j];
    int n = J.n4[j];
    for (int i = blockIdx.x * 256 + threadIdx.x; i < n; i += gridDim.x * 256) {
      float4 v = s[i];
      ushort4 u;
      u.x = f2bf(v.x); u.y = f2bf(v.y); u.z = f2bf(v.z); u.w = f2bf(v.w);
      d[i] = u;
    }
  }
}

__global__ void init_h(const float* __restrict__ in, float* __restrict__ hf,
                       unsigned short* __restrict__ hb, int n4)
{
  int i = blockIdx.x * 256 + threadIdx.x;
  if (i < n4) {
    float4 v = ((const float4*)in)[i];
    ((float4*)hf)[i] = v;
    ushort4 u;
    u.x = f2bf(v.x); u.y = f2bf(v.y); u.z = f2bf(v.z); u.w = f2bf(v.w);
    ((ushort4*)hb)[i] = u;
  }
}

// ---------------- A[t] = sum_l Gv*Gu*Ww + bw ----------------
__global__ __launch_bounds__(128) void gate_dot(
    const float* __restrict__ Gv, const float* __restrict__ Gu, int ld,
    const float* __restrict__ Ww, const float* __restrict__ bw,
    float* __restrict__ A)
{
  const int t = blockIdx.x, l = threadIdx.x;
  float v = Gv[(size_t)t * ld + l] * Gu[(size_t)t * ld + l] * Ww[l];
  v = wave_sum64(v);
  __shared__ float red[2];
  if ((l & 63) == 0) red[l >> 6] = v;
  __syncthreads();
  if (l == 0) A[t] = red[0] + red[1] + bw[0];
}

// ------- contiguous-segment softmax + weighted pooled sum (D=512) -------
__global__ __launch_bounds__(256) void seg_pool(
    const float* __restrict__ A, const float* __restrict__ X,
    float* __restrict__ w_out, float* __restrict__ out, int seg_len)
{
  const int s = blockIdx.x, tid = threadIdx.x;
  __shared__ float ws[16];
  if (tid < 64) {
    float a = (tid < seg_len) ? A[s * seg_len + tid] : -1e30f;
    float mx = a;
#pragma unroll
    for (int o = 1; o < 16; o <<= 1) mx = fmaxf(mx, __shfl_xor(mx, o));
    float e = (tid < seg_len) ? expf(a - mx) : 0.f;
    float se = e;
#pragma unroll
    for (int o = 1; o < 16; o <<= 1) se += __shfl_xor(se, o);
    if (tid < seg_len) {
      float w = e / se;
      ws[tid] = w;
      w_out[s * seg_len + tid] = w;
    }
  }
  __syncthreads();
  for (int d = tid; d < 512; d += 256) {
    float acc = 0.f;
    for (int i = 0; i < seg_len; i++)
      acc = fmaf(ws[i], X[(size_t)(s * seg_len + i) * 512 + d], acc);
    out[(size_t)s * 512 + d] = acc;
  }
}

// ======================= CNN head (channels-last [n][L][C=128]) =======================

__global__ void conv1_bnT(
    const float* __restrict__ x, const float* __restrict__ K4,
    const float* __restrict__ bias, const float* __restrict__ g,
    const float* __restrict__ bb, unsigned short* __restrict__ y)
{
  int idx = blockIdx.x * 256 + threadIdx.x;   // (n*512+i)*128+o
  int o = idx & 127, i = (idx >> 7) & 511, n = idx >> 16;
  const float* xp = x + n * 512;
  float acc = bias[o];
#pragma unroll
  for (int k = 0; k < 4; k++) {
    int p = i + k - 1;
    float xv = (p >= 0 && p < 512) ? xp[p] : 0.f;
    acc = fmaf(xv, K4[o * 4 + k], acc);
  }
  float sc = g[o] * rsqrtf(1.f + 1e-5f);
  y[idx] = f2bf(fmaxf(fmaf(acc, sc, bb[o]), 0.f));
}

__global__ void reorder_w(const float* __restrict__ Kc, unsigned short* __restrict__ Wr,
                          int KS, int total)
{
  int idx = blockIdx.x * 256 + threadIdx.x;
  if (idx < total) {
    int c = idx & 127;
    int kk = (idx >> 7) % KS;
    int o = idx / (128 * KS);
    Wr[idx] = f2bf(Kc[(o * 128 + c) * KS + kk]);
  }
}

template<int KS, int PAD, int LEN, int OUTF>
__global__ __launch_bounds__(256) void convT_mfma(
    const unsigned short* __restrict__ X, const unsigned short* __restrict__ Wr,
    const float* __restrict__ bias, const float* __restrict__ g,
    const float* __restrict__ bb,
    unsigned short* __restrict__ Yb, float* __restrict__ Yf)
{
  constexpr int ROWS = 64 + KS - 1;
  __shared__ __align__(16) unsigned short XT[ROWS * 128];
  const int tid = threadIdx.x;
  const int w = tid >> 6, lane = tid & 63;
  const int l15 = lane & 15, l4 = lane >> 4;
  const int i0 = (blockIdx.x >> 1) * 64;
  const int o0 = (blockIdx.x & 1) * 64;
  const int n = blockIdx.y;

  {
    const int c = (tid & 15) * 8;
    for (int r = tid >> 4; r < ROWS; r += 16) {
      int gi = i0 - PAD + r;
      bf16x8 v = {};
      if (gi >= 0 && gi < LEN)
        v = *(const bf16x8*)&X[((size_t)n * LEN + gi) * 128 + c];
      int byte = r * 256 + c * 2;
      *(bf16x8*)((char*)XT + swz256(byte)) = v;
    }
  }
  __syncthreads();

  f32x4 acc[4] = {};
#pragma unroll
  for (int kk = 0; kk < KS; kk++) {
#pragma unroll
    for (int cc = 0; cc < 4; cc++) {
      int r = w * 16 + l15 + kk;
      int byte = r * 256 + cc * 64 + l4 * 16;
      bf16x8 a = *(const bf16x8*)((const char*)XT + swz256(byte));
      bf16x8 bfr[4];
#pragma unroll
      for (int nb = 0; nb < 4; nb++)
        bfr[nb] = *(const bf16x8*)&Wr[(size_t)(o0 + nb * 16 + l15) * (KS * 128) +
                                      kk * 128 + cc * 32 + l4 * 8];
#pragma unroll
      for (int nb = 0; nb < 4; nb++)
        acc[nb] = __builtin_amdgcn_mfma_f32_16x16x32_bf16(a, bfr[nb], acc[nb], 0, 0, 0);
    }
  }

#pragma unroll
  for (int nb = 0; nb < 4; nb++) {
    int o = o0 + nb * 16 + l15;
    float sc = g[o] * rsqrtf(1.f + 1e-5f);
    float bs = bias[o], bo_ = bb[o];
#pragma unroll
    for (int rr = 0; rr < 4; rr++) {
      int i = i0 + w * 16 + l4 * 4 + rr;
      float v = fmaxf(fmaf(acc[nb][rr] + bs, sc, bo_), 0.f);
      size_t oidx = ((size_t)n * LEN + i) * 128 + o;
      if (OUTF) Yf[oidx] = v;
      else Yb[oidx] = f2bf(v);
    }
  }
}

__global__ void avgpool2_bf(const unsigned short* __restrict__ x,
                            unsigned short* __restrict__ y, int nI, int nTot4)
{
  int j = blockIdx.x * 256 + threadIdx.x;
  if (j >= nTot4) return;
  int cq = j & 31;
  int i = (j >> 5) % nI;
  int n = j / (nI * 32);
  const ushort4* a = (const ushort4*)&x[(((size_t)n * nI + i) * 2) * 128 + cq * 4];
  const ushort4* b = (const ushort4*)&x[(((size_t)n * nI + i) * 2 + 1) * 128 + cq * 4];
  ushort4 ua = *a, ub = *b;
  ushort4 r;
  r.x = f2bf(0.5f * (bf2f(ua.x) + bf2f(ub.x)));
  r.y = f2bf(0.5f * (bf2f(ua.y) + bf2f(ub.y)));
  r.z = f2bf(0.5f * (bf2f(ua.z) + bf2f(ub.z)));
  r.w = f2bf(0.5f * (bf2f(ua.w) + bf2f(ub.w)));
  ((ushort4*)y)[j] = r;
}

__global__ void pool3_transpose(const float* __restrict__ x, float* __restrict__ y)
{
  int j = blockIdx.x * 256 + threadIdx.x;   // n*16384 + c*128 + i
  if (j >= 524288) return;
  int i = j & 127, c = (j >> 7) & 127, n = j >> 14;
  const float* b = x + ((size_t)n * 256 + 2 * i) * 128 + c;
  y[j] = 0.5f * (b[0] + b[128]);
}

__global__ __launch_bounds__(256) void fc1_kernel(
    const float* __restrict__ x, const float* __restrict__ W,
    const float* __restrict__ bias, const float* __restrict__ g,
    const float* __restrict__ bb, float* __restrict__ y)
{
  int o = blockIdx.x & 255, n = blockIdx.x >> 8;
  const float* xp = x + (size_t)n * 16384;
  const float* wp = W + (size_t)o * 16384;
  float s = 0.f;
  for (int j = threadIdx.x * 4; j < 16384; j += 1024) {
    float4 a = *(const float4*)(xp + j);
    float4 b = *(const float4*)(wp + j);
    s = fmaf(a.x, b.x, s); s = fmaf(a.y, b.y, s);
    s = fmaf(a.z, b.z, s); s = fmaf(a.w, b.w, s);
  }
  s = wave_sum64(s);
  __shared__ float red[4];
  if ((threadIdx.x & 63) == 0) red[threadIdx.x >> 6] = s;
  __syncthreads();
  if (threadIdx.x == 0) {
    float v = red[0] + red[1] + red[2] + red[3] + bias[o];
    v = fmaxf(v, 0.f);
    y[n * 256 + o] = fmaf(v, g[o] * rsqrtf(1.f + 1e-5f), bb[o]);
  }
}

__global__ __launch_bounds__(256) void fc2_kernel(
    const float* __restrict__ x, const float* __restrict__ W,
    const float* __restrict__ bias, const float* __restrict__ g,
    const float* __restrict__ bb, float* __restrict__ y)
{
  int o = blockIdx.x & 127, n = blockIdx.x >> 7;
  float s = x[n * 256 + threadIdx.x] * W[o * 256 + threadIdx.x];
  s = wave_sum64(s);
  __shared__ float red[4];
  if ((threadIdx.x & 63) == 0) red[threadIdx.x >> 6] = s;
  __syncthreads();
  if (threadIdx.x == 0) {
    float v = red[0] + red[1] + red[2] + red[3] + bias[o];
    v = fmaxf(v, 0.f);
    y[n * 128 + o] = fmaf(v, g[o] * rsqrtf(1.f + 1e-5f), bb[o]);
  }
}

__global__ __launch_bounds__(64) void fc3_kernel(
    const float* __restrict__ x, const float* __restrict__ W,
    const float* __restrict__ bias, float* __restrict__ out)
{
  int n = threadIdx.x;
  if (n < 32) {
    float s = bias[0];
    for (int k = 0; k < 128; k++) s = fmaf(x[n * 128 + k], W[k], s);
    float p = 1.f / (1.f + expf(-s));
    out[n] = p;
    out[32 + n] = (p >= 0.5f) ? 1.f : 0.f;
  }
}

extern "C" void kernel_launch(void* const* d_in, const int* in_sizes, int n_in,
                              void* d_out, int out_size, void* d_ws, size_t ws_size,
                              hipStream_t stream)
{
  const float* datas = (const float*)d_in[0];
  const float* Wqkv = (const float*)d_in[6];
  const float* bqkv = (const float*)d_in[7];
  const float* Wo   = (const float*)d_in[8];
  const float* bo   = (const float*)d_in[9];
  const float* ln1g = (const float*)d_in[10];
  const float* ln1b = (const float*)d_in[11];
  const float* W1   = (const float*)d_in[12];
  const float* b1   = (const float*)d_in[13];
  const float* W2   = (const float*)d_in[14];
  const float* b2   = (const float*)d_in[15];
  const float* ln2g = (const float*)d_in[16];
  const float* ln2b = (const float*)d_in[17];
  const float* Wv1  = (const float*)d_in[18];
  const float* bv1  = (const float*)d_in[19];
  const float* Wu1  = (const float*)d_in[20];
  const float* bu1  = (const float*)d_in[21];
  const float* Ww1  = (const float*)d_in[22];
  const float* bw1  = (const float*)d_in[23];
  const float* Wv2  = (const float*)d_in[24];
  const float* bv2  = (const float*)d_in[25];
  const float* Wu2  = (const float*)d_in[26];
  const float* bu2  = (const float*)d_in[27];
  const float* Ww2  = (const float*)d_in[28];
  const float* bw2  = (const float*)d_in[29];
  const float* Kc1  = (const float*)d_in[30];
  const float* bc1  = (const float*)d_in[31];
  const float* gc1  = (const float*)d_in[32];
  const float* bb1  = (const float*)d_in[33];
  const float* Kc2  = (const float*)d_in[34];
  const float* bc2  = (const float*)d_in[35];
  const float* gc2  = (const float*)d_in[36];
  const float* bb2  = (const float*)d_in[37];
  const float* Kc3  = (const float*)d_in[38];
  const float* bc3  = (const float*)d_in[39];
  const float* gc3  = (const float*)d_in[40];
  const float* bb3  = (const float*)d_in[41];
  const float* Wf1  = (const float*)d_in[42];
  const float* bf1  = (const float*)d_in[43];
  const float* g4   = (const float*)d_in[44];
  const float* b4   = (const float*)d_in[45];
  const float* Wf2  = (const float*)d_in[46];
  const float* bf2  = (const float*)d_in[47];
  const float* g5   = (const float*)d_in[48];
  const float* b5   = (const float*)d_in[49];
  const float* Wf3  = (const float*)d_in[50];
  const float* bf3  = (const float*)d_in[51];

  float* ws = (float*)d_ws;
  float* h_f32 = ws;                              // 2,097,152 f
  float* R2f   = ws + 2097152;                    // 6,291,456 f
  unsigned short* h_bf = (unsigned short*)(ws + 8388608);   // 2,097,152 ush
  unsigned short* wbuf = (unsigned short*)(ws + 9437184);   // 3,473,408 ush
  float* biasG = ws + 11173888;                   // 256 f
  unsigned short* VTg = (unsigned short*)(ws + 11174144);   // 2,097,152 ush (V^T [512][4096])

  unsigned short* qkv_bf = (unsigned short*)R2f;
  unsigned short* O_bf   = (unsigned short*)(R2f + 3145728);
  unsigned short* ff1_bf = (unsigned short*)R2f;
  float* projf = R2f + 4194304;

  unsigned short* WqkvB = wbuf;                 // 786,432 (per-layer reuse)
  unsigned short* WoB   = wbuf + 786432;        // 262,144
  unsigned short* W1B   = wbuf + 1048576;       // 1,048,576
  unsigned short* W2B   = wbuf + 2097152;       // 1,048,576
  unsigned short* WvuB  = wbuf + 3145728;       // 131,072 (persistent tail)
  unsigned short* Wr2B  = wbuf + 3276800;       // 81,920
  unsigned short* Wr3B  = wbuf + 3358720;       // 114,688

  float* out_f = (float*)d_out;

  init_h<<<2048, 256, 0, stream>>>(datas, h_f32, h_bf, 524288);
  reorder_w<<<320, 256, 0, stream>>>(Kc2, Wr2B, 5, 81920);
  reorder_w<<<448, 256, 0, stream>>>(Kc3, Wr3B, 7, 114688);
  hipMemcpyAsync(biasG, bv1, 128 * sizeof(float), hipMemcpyDeviceToDevice, stream);
  hipMemcpyAsync(biasG + 128, bu1, 128 * sizeof(float), hipMemcpyDeviceToDevice, stream);

  for (int l = 0; l < 2; l++) {
    CastJobs J{};
    J.src[0] = Wqkv + (size_t)l * 786432;  J.dst[0] = WqkvB; J.n4[0] = 196608;
    J.src[1] = Wo   + (size_t)l * 262144;  J.dst[1] = WoB;   J.n4[1] = 65536;
    J.src[2] = W1   + (size_t)l * 1048576; J.dst[2] = W1B;   J.n4[2] = 262144;
    J.src[3] = W2   + (size_t)l * 1048576; J.dst[3] = W2B;   J.n4[3] = 262144;
    J.njobs = 4;
    if (l == 0) {
      J.src[4] = Wv1; J.dst[4] = WvuB;         J.n4[4] = 16384;
      J.src[5] = Wu1; J.dst[5] = WvuB + 65536; J.n4[5] = 16384;
      J.njobs = 6;
    }
    cast_multi<<<512, 256, 0, stream>>>(J);

    // qkv: Q,K -> qkv_bf [t][1536]; V -> VTg [h*64+d][t]
    mgemm<0, 1, 1><<<dim3(12, 32), 256, 0, stream>>>(
        h_bf, WqkvB, bqkv + (size_t)l * 1536, nullptr, qkv_bf, VTg, 4096, 1536, 512);
    attn_mfma<<<dim3(64, 8), 256, 0, stream>>>(qkv_bf, VTg, O_bf);
    mgemm<0, 0, 0><<<dim3(4, 32), 256, 0, stream>>>(
        O_bf, WoB, bo + (size_t)l * 512, projf, nullptr, nullptr, 4096, 512, 512);
    residual_ln<<<4096, 64, 0, stream>>>(projf, h_f32, ln1g + l * 512, ln1b + l * 512,
                                         h_f32, h_bf);
    mgemm<1, 1, 0><<<dim3(16, 32), 256, 0, stream>>>(
        h_bf, W1B, b1 + (size_t)l * 2048, nullptr, ff1_bf, nullptr, 4096, 2048, 512);
    mgemm<0, 0, 0><<<dim3(4, 32), 256, 0, stream>>>(
        ff1_bf, W2B, b2 + (size_t)l * 512, projf, nullptr, nullptr, 4096, 512, 2048);
    residual_ln<<<4096, 64, 0, stream>>>(projf, h_f32, ln2g + l * 512, ln2b + l * 512,
                                         h_f32, h_bf);
  }

  // ---- gated pooling (stage 1: fused tanh/sigmoid GEMM, N=256) ----
  float* G    = R2f;              // 4096 x 256
  float* A1   = R2f + 1048576;
  float* out1 = R2f + 1052672;
  float* Gv2  = R2f + 1183744;
  float* Gu2  = R2f + 1216512;
  float* A2   = R2f + 1249280;
  float* out2 = R2f + 1249536;

  mgemm<4, 0, 0><<<dim3(2, 32), 256, 0, stream>>>(
      h_bf, WvuB, biasG, G, nullptr, nullptr, 4096, 256, 512);
  gate_dot<<<4096, 128, 0, stream>>>(G, G + 128, 256, Ww1, bw1, A1);
  seg_pool<<<256, 256, 0, stream>>>(A1, h_f32, out_f + 64, out1, 16);

  gemm_bias<2><<<dim3(2, 4), 256, 0, stream>>>(out1, Wv2, bv2, Gv2, 256, 128, 512);
  gemm_bias<3><<<dim3(2, 4), 256, 0, stream>>>(out1, Wu2, bu2, Gu2, 256, 128, 512);
  gate_dot<<<256, 128, 0, stream>>>(Gv2, Gu2, 128, Ww2, bw2, A2);
  seg_pool<<<32, 256, 0, stream>>>(A2, out1, out_f + 4160, out2, 8);

  // ---- CNN head, channels-last ----
  unsigned short* c1T = (unsigned short*)(R2f + 1310720);  // 2,097,152 ush
  unsigned short* c2T = (unsigned short*)(R2f + 2359296);  // 2,097,152 ush
  unsigned short* p2T = (unsigned short*)(R2f + 3407872);  // 1,048,576 ush
  float* c3T = R2f + 3932160;                              // 1,048,576 f
  float* p3R = R2f + 4980736;                              // 524,288 f
  float* f1  = R2f + 5505024;
  float* f2  = R2f + 5513216;

  conv1_bnT<<<8192, 256, 0, stream>>>(out2, Kc1, bc1, gc1, bb1, c1T);
  convT_mfma<5, 2, 512, 0><<<dim3(16, 32), 256, 0, stream>>>(
      c1T, Wr2B, bc2, gc2, bb2, c2T, nullptr);
  avgpool2_bf<<<1024, 256, 0, stream>>>(c2T, p2T, 256, 262144);
  convT_mfma<7, 3, 256, 1><<<dim3(8, 32), 256, 0, stream>>>(
      p2T, Wr3B, bc3, gc3, bb3, nullptr, c3T);
  pool3_transpose<<<2048, 256, 0, stream>>>(c3T, p3R);
  fc1_kernel<<<8192, 256, 0, stream>>>(p3R, Wf1, bf1, g4, b4, f1);
  fc2_kernel<<<4096, 256, 0, stream>>>(f1, Wf2, bf2, g5, b5, f2);
  fc3_kernel<<<1, 64, 0, stream>>>(f2, Wf3, bf3, out_f);
}

// Round 12
// 594.765 us; speedup vs baseline: 1.1164x; 1.0932x over previous
//
#include <hip/hip_runtime.h>
#include <math.h>

// T=4096, M=512, NH=8, HD=64, FF=2048, NL=2, NI=256 (16 tok/seg), NO=32 (8 seg/outer)

typedef float f32x4 __attribute__((ext_vector_type(4)));
typedef __bf16 bf16x8 __attribute__((ext_vector_type(8)));

__device__ __forceinline__ unsigned short f2bf(float x) {
  unsigned int u = __builtin_bit_cast(unsigned int, x);
  u += 0x7FFFu + ((u >> 16) & 1u);
  return (unsigned short)(u >> 16);
}
__device__ __forceinline__ float bf2f(unsigned short u) {
  unsigned int x = ((unsigned int)u) << 16;
  return __builtin_bit_cast(float, x);
}
// pack two f32 -> two bf16 (RTNE) in one instruction
__device__ __forceinline__ unsigned int pk_bf16(float a, float b) {
  unsigned int r;
  asm("v_cvt_pk_bf16_f32 %0, %1, %2" : "=v"(r) : "v"(a), "v"(b));
  return r;
}

__device__ __forceinline__ float wave_sum64(float v) {
#pragma unroll
  for (int o = 32; o > 0; o >>= 1) v += __shfl_xor(v, o);
  return v;
}

// XOR swizzle for LDS tiles with 128-byte rows (64 bf16/row).
__device__ __forceinline__ int swz(int byte) {
  return byte ^ (((byte >> 7) & 7) << 4);
}
// XOR swizzle for LDS tiles with 256-byte rows (128 bf16/row).
__device__ __forceinline__ int swz256(int byte) {
  return byte ^ (((byte >> 8) & 7) << 4);
}

// ============ bf16 MFMA GEMM (round-9 version: reg-staged, swizzled, prefetch) ============
// ACT: 0 none, 1 relu, 2 tanh, 3 sigmoid, 4 col<128?tanh:sigmoid (fused gate)
// VSPLIT: cols >= 1024 go to VT[col-1024][row] (bf16, packed 4-row stores).
template<int ACT, int OUTBF, int VSPLIT>
__global__ __launch_bounds__(256) void mgemm(
    const unsigned short* __restrict__ A, const unsigned short* __restrict__ B,
    const float* __restrict__ bias, float* __restrict__ Cf,
    unsigned short* __restrict__ Cb, unsigned short* __restrict__ VT,
    int M, int N, int K)
{
  __shared__ __align__(16) unsigned short As[128 * 64];
  __shared__ __align__(16) unsigned short Bs[128 * 64];
  const int tid = threadIdx.x;
  const int wid = tid >> 6, lane = tid & 63;
  const int wm = wid >> 1, wn = wid & 1;
  const int l15 = lane & 15, l4 = lane >> 4;
  const int m0 = blockIdx.y * 128, n0 = blockIdx.x * 128;
  const int srow = tid >> 3;
  const int scol = (tid & 7) * 8;

  f32x4 acc[4][4] = {};

  bf16x8 ra[4], rb[4];
#pragma unroll
  for (int i = 0; i < 4; i++) {
    ra[i] = *(const bf16x8*)&A[(size_t)(m0 + srow + i * 32) * K + scol];
    rb[i] = *(const bf16x8*)&B[(size_t)(n0 + srow + i * 32) * K + scol];
  }

  for (int k0 = 0; k0 < K; k0 += 64) {
    __syncthreads();   // all waves done reading previous LDS tile
#pragma unroll
    for (int i = 0; i < 4; i++) {
      int byte = (srow + i * 32) * 128 + scol * 2;
      *(bf16x8*)((char*)As + swz(byte)) = ra[i];
      *(bf16x8*)((char*)Bs + swz(byte)) = rb[i];
    }
    __syncthreads();   // LDS ready
    if (k0 + 64 < K) { // prefetch next tile; latency hides under MFMA below
#pragma unroll
      for (int i = 0; i < 4; i++) {
        ra[i] = *(const bf16x8*)&A[(size_t)(m0 + srow + i * 32) * K + k0 + 64 + scol];
        rb[i] = *(const bf16x8*)&B[(size_t)(n0 + srow + i * 32) * K + k0 + 64 + scol];
      }
    }
#pragma unroll
    for (int kc = 0; kc < 2; kc++) {
      bf16x8 af[4], bf_[4];
#pragma unroll
      for (int i = 0; i < 4; i++) {
        int byteA = (wm * 64 + i * 16 + l15) * 128 + kc * 64 + l4 * 16;
        af[i] = *(const bf16x8*)((const char*)As + swz(byteA));
        int byteB = (wn * 64 + i * 16 + l15) * 128 + kc * 64 + l4 * 16;
        bf_[i] = *(const bf16x8*)((const char*)Bs + swz(byteB));
      }
#pragma unroll
      for (int i = 0; i < 4; i++)
#pragma unroll
        for (int j = 0; j < 4; j++)
          acc[i][j] = __builtin_amdgcn_mfma_f32_16x16x32_bf16(af[i], bf_[j], acc[i][j], 0, 0, 0);
    }
  }
#pragma unroll
  for (int i = 0; i < 4; i++) {
#pragma unroll
    for (int j = 0; j < 4; j++) {
      int col = n0 + wn * 64 + j * 16 + l15;
      float bv = bias[col];
      if (VSPLIT && col >= 1024) {
        float x0 = acc[i][j][0] + bv, x1 = acc[i][j][1] + bv;
        float x2 = acc[i][j][2] + bv, x3 = acc[i][j][3] + bv;
        uint2 pv;
        pv.x = pk_bf16(x0, x1);
        pv.y = pk_bf16(x2, x3);
        int row0 = m0 + wm * 64 + i * 16 + l4 * 4;
        *(uint2*)&VT[(size_t)(col - 1024) * 4096 + row0] = pv;
      } else {
#pragma unroll
        for (int r = 0; r < 4; r++) {
          int row = m0 + wm * 64 + i * 16 + l4 * 4 + r;
          float x = acc[i][j][r] + bv;
          if (ACT == 1) x = fmaxf(x, 0.f);
          if (ACT == 2) x = tanhf(x);
          if (ACT == 3) x = 1.f / (1.f + expf(-x));
          if (ACT == 4) x = (col < 128) ? tanhf(x) : (1.f / (1.f + expf(-x)));
          if (OUTBF) Cb[(size_t)row * N + col] = f2bf(x);
          else       Cf[(size_t)row * N + col] = x;
        }
      }
    }
  }
}

// ============ MFMA flash attention (round-9 version, verbatim) ============
__global__ __launch_bounds__(256) void attn_mfma(
    const unsigned short* __restrict__ qkv, const unsigned short* __restrict__ VT,
    unsigned short* __restrict__ O)
{
  __shared__ __align__(16) unsigned short Ks[64 * 64];   // [k][d]   swizzled
  __shared__ __align__(16) unsigned short VTs[64 * 64];  // [d][k]   swizzled
  __shared__ __align__(16) unsigned short Ps[64 * 64];   // [q][k]   swizzled
  const int tid = threadIdx.x;
  const int w = tid >> 6, lane = tid & 63;
  const int l15 = lane & 15, l4 = lane >> 4;
  const int h = blockIdx.y, qt = blockIdx.x;
  const float C = 0.18033688011112042f;   // 0.125 * log2(e)

  bf16x8 qf[2];
#pragma unroll
  for (int kc = 0; kc < 2; kc++)
    qf[kc] = *(const bf16x8*)&qkv[(size_t)(qt * 64 + w * 16 + l15) * 1536 + h * 64 + kc * 32 + l4 * 8];

  f32x4 oaccT[4] = {};
  float m = -1e30f, l = 0.f;

  const int sr = tid >> 3;
  const int sc = (tid & 7) * 8;
  const int vd = tid >> 2;            // 0..63
  const int vk0 = (tid & 3) * 16;     // 0,16,32,48

  const unsigned short* kp0 = qkv + (size_t)sr * 1536 + 512 + h * 64 + sc;
  const unsigned short* kp1 = kp0 + 32 * 1536;
  const unsigned short* vp = VT + (size_t)(h * 64 + vd) * 4096 + vk0;

  bf16x8 rk0 = *(const bf16x8*)kp0;
  bf16x8 rk1 = *(const bf16x8*)kp1;
  bf16x8 rv0 = *(const bf16x8*)vp;
  bf16x8 rv1 = *(const bf16x8*)(vp + 8);

  for (int kt = 0; kt < 64; kt++) {
    __syncthreads();   // previous tile fully consumed
    {
      int b0 = sr * 128 + sc * 2;
      *(bf16x8*)((char*)Ks + swz(b0)) = rk0;
      int b1 = (sr + 32) * 128 + sc * 2;
      *(bf16x8*)((char*)Ks + swz(b1)) = rk1;
      int vb0 = vd * 128 + vk0 * 2;
      *(bf16x8*)((char*)VTs + swz(vb0)) = rv0;
      *(bf16x8*)((char*)VTs + swz(vb0 + 16)) = rv1;
    }
    __syncthreads();   // LDS ready
    if (kt < 63) {     // prefetch next tile (bit-exact; hides HBM latency)
      kp0 += 64 * 1536; kp1 += 64 * 1536; vp += 64;
      rk0 = *(const bf16x8*)kp0;
      rk1 = *(const bf16x8*)kp1;
      rv0 = *(const bf16x8*)vp;
      rv1 = *(const bf16x8*)(vp + 8);
    }

    // S^T = mfma(A=K, B=Q)
    f32x4 st[4] = {};
    __builtin_amdgcn_s_setprio(1);
#pragma unroll
    for (int kc = 0; kc < 2; kc++) {
#pragma unroll
      for (int nb = 0; nb < 4; nb++) {
        int byte = (nb * 16 + l15) * 128 + kc * 64 + l4 * 16;
        bf16x8 kf = *(const bf16x8*)((const char*)Ks + swz(byte));
        st[nb] = __builtin_amdgcn_mfma_f32_16x16x32_bf16(kf, qf[kc], st[nb], 0, 0, 0);
      }
    }
    __builtin_amdgcn_s_setprio(0);

    // lane-local online softmax (always rescale)
    float tm = -1e30f;
#pragma unroll
    for (int nb = 0; nb < 4; nb++)
#pragma unroll
      for (int r = 0; r < 4; r++) tm = fmaxf(tm, st[nb][r]);
    tm = fmaxf(tm, __shfl_xor(tm, 16));
    tm = fmaxf(tm, __shfl_xor(tm, 32));
    float mn = fmaxf(m, tm);
    float alpha = exp2f((m - mn) * C);
    float e[4][4];
    float ps = 0.f;
#pragma unroll
    for (int nb = 0; nb < 4; nb++)
#pragma unroll
      for (int r = 0; r < 4; r++) {
        e[nb][r] = exp2f((st[nb][r] - mn) * C);
        ps += e[nb][r];
      }
    ps += __shfl_xor(ps, 16);
    ps += __shfl_xor(ps, 32);
    l = l * alpha + ps;
    m = mn;
#pragma unroll
    for (int nb = 0; nb < 4; nb++) oaccT[nb] *= alpha;

    // P rows -> Ps[q][k]
#pragma unroll
    for (int nb = 0; nb < 4; nb++) {
      uint2 pr;
      pr.x = pk_bf16(e[nb][0], e[nb][1]);
      pr.y = pk_bf16(e[nb][2], e[nb][3]);
      int byte = (w * 16 + l15) * 128 + (nb * 16 + l4 * 4) * 2;
      *(uint2*)((char*)Ps + swz(byte)) = pr;
    }

    // O^T += mfma(A=V^T, B=P)
#pragma unroll
    for (int kc = 0; kc < 2; kc++) {
      int bp = (w * 16 + l15) * 128 + kc * 64 + l4 * 16;
      bf16x8 pb = *(const bf16x8*)((const char*)Ps + swz(bp));
      __builtin_amdgcn_s_setprio(1);
#pragma unroll
      for (int nb = 0; nb < 4; nb++) {
        int bv = (nb * 16 + l15) * 128 + kc * 64 + l4 * 16;
        bf16x8 vf = *(const bf16x8*)((const char*)VTs + swz(bv));
        oaccT[nb] = __builtin_amdgcn_mfma_f32_16x16x32_bf16(vf, pb, oaccT[nb], 0, 0, 0);
      }
      __builtin_amdgcn_s_setprio(0);
    }
  }

  float linv = 1.f / l;
  int row = qt * 64 + w * 16 + l15;
#pragma unroll
  for (int nb = 0; nb < 4; nb++) {
    uint2 ov;
    ov.x = pk_bf16(oaccT[nb][0] * linv, oaccT[nb][1] * linv);
    ov.y = pk_bf16(oaccT[nb][2] * linv, oaccT[nb][3] * linv);
    int col = h * 64 + nb * 16 + l4 * 4;
    *(uint2*)&O[(size_t)row * 512 + col] = ov;
  }
}

// ---------------- fp32 GEMM (tiny stage-2 gating) ----------------
template<int ACT>
__global__ __launch_bounds__(256) void gemm_bias(
    const float* __restrict__ A, const float* __restrict__ B,
    const float* __restrict__ bias, float* __restrict__ C,
    int M, int N, int K)
{
  __shared__ float As[16][68];
  __shared__ float Bs[16][68];
  const int tid = threadIdx.x;
  const int tx = tid & 15, ty = tid >> 4;
  const int m0 = blockIdx.y * 64, n0 = blockIdx.x * 64;
  const int lr = tid >> 2;
  const int lk = (tid & 3) * 4;
  float acc[4][4] = {};
  for (int k0 = 0; k0 < K; k0 += 16) {
    __syncthreads();
    float4 av = *(const float4*)&A[(size_t)(m0 + lr) * K + k0 + lk];
    float4 bv = *(const float4*)&B[(size_t)(n0 + lr) * K + k0 + lk];
    As[lk + 0][lr] = av.x; As[lk + 1][lr] = av.y; As[lk + 2][lr] = av.z; As[lk + 3][lr] = av.w;
    Bs[lk + 0][lr] = bv.x; Bs[lk + 1][lr] = bv.y; Bs[lk + 2][lr] = bv.z; Bs[lk + 3][lr] = bv.w;
    __syncthreads();
#pragma unroll
    for (int k = 0; k < 16; k++) {
      float a[4], b[4];
#pragma unroll
      for (int i = 0; i < 4; i++) a[i] = As[k][ty * 4 + i];
#pragma unroll
      for (int j = 0; j < 4; j++) b[j] = Bs[k][tx * 4 + j];
#pragma unroll
      for (int i = 0; i < 4; i++)
#pragma unroll
        for (int j = 0; j < 4; j++)
          acc[i][j] = fmaf(a[i], b[j], acc[i][j]);
    }
  }
#pragma unroll
  for (int i = 0; i < 4; i++)
#pragma unroll
    for (int j = 0; j < 4; j++) {
      float x = acc[i][j] + bias[n0 + tx * 4 + j];
      if (ACT == 1) x = fmaxf(x, 0.f);
      if (ACT == 2) x = tanhf(x);
      if (ACT == 3) x = 1.f / (1.f + expf(-x));
      C[(size_t)(m0 + ty * 4 + i) * N + n0 + tx * 4 + j] = x;
    }
}

// ---------------- LayerNorm(x + res), writes f32 + bf16 ----------------
__global__ __launch_bounds__(64) void residual_ln(
    const float* __restrict__ x, const float* __restrict__ res,
    const float* __restrict__ g, const float* __restrict__ b,
    float* __restrict__ out, unsigned short* __restrict__ out_bf)
{
  const int row = blockIdx.x, lane = threadIdx.x;
  const float* xp = x + (size_t)row * 512;
  const float* rp = res + (size_t)row * 512;
  float v[8];
  float s = 0.f;
#pragma unroll
  for (int i = 0; i < 8; i++) { v[i] = xp[lane + 64 * i] + rp[lane + 64 * i]; s += v[i]; }
  s = wave_sum64(s);
  float mu = s * (1.f / 512.f);
  float vs = 0.f;
#pragma unroll
  for (int i = 0; i < 8; i++) { float d = v[i] - mu; vs = fmaf(d, d, vs); }
  vs = wave_sum64(vs);
  float rstd = rsqrtf(vs * (1.f / 512.f) + 1e-5f);
  float* op = out + (size_t)row * 512;
  unsigned short* ob = out_bf + (size_t)row * 512;
#pragma unroll
  for (int i = 0; i < 8; i++) {
    float y = (v[i] - mu) * rstd * g[lane + 64 * i] + b[lane + 64 * i];
    op[lane + 64 * i] = y;
    ob[lane + 64 * i] = f2bf(y);
  }
}

// ---------------- multi-job f32 -> bf16 cast (one launch per batch) ----------------
struct CastJobs {
  const float* src[6];
  unsigned short* dst[6];
  int n4[6];
  int njobs;
};

__global__ void cast_multi(CastJobs J)
{
  for (int j = 0; j < J.njobs; j++) {
    const float4* s = (const float4*)J.src[j];
    ushort4* d = (ushort4*)J.dst[j];
    int n = J.n4[j];
    for (int i = blockIdx.x * 256 + threadIdx.x; i < n; i += gridDim.x * 256) {
      float4 v = s[i];
      ushort4 u;
      u.x = f2bf(v.x); u.y = f2bf(v.y); u.z = f2bf(v.z); u.w = f2bf(v.w);
      d[i] = u;
    }
  }
}

__global__ void init_h(const float* __restrict__ in, float* __restrict__ hf,
                       unsigned short* __restrict__ hb, int n4)
{
  int i = blockIdx.x * 256 + threadIdx.x;
  if (i < n4) {
    float4 v = ((const float4*)in)[i];
    ((float4*)hf)[i] = v;
    ushort4 u;
    u.x = f2bf(v.x); u.y = f2bf(v.y); u.z = f2bf(v.z); u.w = f2bf(v.w);
    ((ushort4*)hb)[i] = u;
  }
}

// ---------------- A[t] = sum_l Gv*Gu*Ww + bw ----------------
__global__ __launch_bounds__(128) void gate_dot(
    const float* __restrict__ Gv, const float* __restrict__ Gu, int ld,
    const float* __restrict__ Ww, const float* __restrict__ bw,
    float* __restrict__ A)
{
  const int t = blockIdx.x, l = threadIdx.x;
  float v = Gv[(size_t)t * ld + l] * Gu[(size_t)t * ld + l] * Ww[l];
  v = wave_sum64(v);
  __shared__ float red[2];
  if ((l & 63) == 0) red[l >> 6] = v;
  __syncthreads();
  if (l == 0) A[t] = red[0] + red[1] + bw[0];
}

// ------- contiguous-segment softmax + weighted pooled sum (D=512) -------
__global__ __launch_bounds__(256) void seg_pool(
    const float* __restrict__ A, const float* __restrict__ X,
    float* __restrict__ w_out, float* __restrict__ out, int seg_len)
{
  const int s = blockIdx.x, tid = threadIdx.x;
  __shared__ float ws[16];
  if (tid < 64) {
    float a = (tid < seg_len) ? A[s * seg_len + tid] : -1e30f;
    float mx = a;
#pragma unroll
    for (int o = 1; o < 16; o <<= 1) mx = fmaxf(mx, __shfl_xor(mx, o));
    float e = (tid < seg_len) ? expf(a - mx) : 0.f;
    float se = e;
#pragma unroll
    for (int o = 1; o < 16; o <<= 1) se += __shfl_xor(se, o);
    if (tid < seg_len) {
      float w = e / se;
      ws[tid] = w;
      w_out[s * seg_len + tid] = w;
    }
  }
  __syncthreads();
  for (int d = tid; d < 512; d += 256) {
    float acc = 0.f;
    for (int i = 0; i < seg_len; i++)
      acc = fmaf(ws[i], X[(size_t)(s * seg_len + i) * 512 + d], acc);
    out[(size_t)s * 512 + d] = acc;
  }
}

// ======================= CNN head (channels-last [n][L][C=128]) =======================

__global__ void conv1_bnT(
    const float* __restrict__ x, const float* __restrict__ K4,
    const float* __restrict__ bias, const float* __restrict__ g,
    const float* __restrict__ bb, unsigned short* __restrict__ y)
{
  int idx = blockIdx.x * 256 + threadIdx.x;   // (n*512+i)*128+o
  int o = idx & 127, i = (idx >> 7) & 511, n = idx >> 16;
  const float* xp = x + n * 512;
  float acc = bias[o];
#pragma unroll
  for (int k = 0; k < 4; k++) {
    int p = i + k - 1;
    float xv = (p >= 0 && p < 512) ? xp[p] : 0.f;
    acc = fmaf(xv, K4[o * 4 + k], acc);
  }
  float sc = g[o] * rsqrtf(1.f + 1e-5f);
  y[idx] = f2bf(fmaxf(fmaf(acc, sc, bb[o]), 0.f));
}

__global__ void reorder_w(const float* __restrict__ Kc, unsigned short* __restrict__ Wr,
                          int KS, int total)
{
  int idx = blockIdx.x * 256 + threadIdx.x;
  if (idx < total) {
    int c = idx & 127;
    int kk = (idx >> 7) % KS;
    int o = idx / (128 * KS);
    Wr[idx] = f2bf(Kc[(o * 128 + c) * KS + kk]);
  }
}

template<int KS, int PAD, int LEN, int OUTF>
__global__ __launch_bounds__(256) void convT_mfma(
    const unsigned short* __restrict__ X, const unsigned short* __restrict__ Wr,
    const float* __restrict__ bias, const float* __restrict__ g,
    const float* __restrict__ bb,
    unsigned short* __restrict__ Yb, float* __restrict__ Yf)
{
  constexpr int ROWS = 64 + KS - 1;
  __shared__ __align__(16) unsigned short XT[ROWS * 128];
  const int tid = threadIdx.x;
  const int w = tid >> 6, lane = tid & 63;
  const int l15 = lane & 15, l4 = lane >> 4;
  const int i0 = (blockIdx.x >> 1) * 64;
  const int o0 = (blockIdx.x & 1) * 64;
  const int n = blockIdx.y;

  {
    const int c = (tid & 15) * 8;
    for (int r = tid >> 4; r < ROWS; r += 16) {
      int gi = i0 - PAD + r;
      bf16x8 v = {};
      if (gi >= 0 && gi < LEN)
        v = *(const bf16x8*)&X[((size_t)n * LEN + gi) * 128 + c];
      int byte = r * 256 + c * 2;
      *(bf16x8*)((char*)XT + swz256(byte)) = v;
    }
  }
  __syncthreads();

  f32x4 acc[4] = {};
#pragma unroll
  for (int kk = 0; kk < KS; kk++) {
#pragma unroll
    for (int cc = 0; cc < 4; cc++) {
      int r = w * 16 + l15 + kk;
      int byte = r * 256 + cc * 64 + l4 * 16;
      bf16x8 a = *(const bf16x8*)((const char*)XT + swz256(byte));
      bf16x8 bfr[4];
#pragma unroll
      for (int nb = 0; nb < 4; nb++)
        bfr[nb] = *(const bf16x8*)&Wr[(size_t)(o0 + nb * 16 + l15) * (KS * 128) +
                                      kk * 128 + cc * 32 + l4 * 8];
#pragma unroll
      for (int nb = 0; nb < 4; nb++)
        acc[nb] = __builtin_amdgcn_mfma_f32_16x16x32_bf16(a, bfr[nb], acc[nb], 0, 0, 0);
    }
  }

#pragma unroll
  for (int nb = 0; nb < 4; nb++) {
    int o = o0 + nb * 16 + l15;
    float sc = g[o] * rsqrtf(1.f + 1e-5f);
    float bs = bias[o], bo_ = bb[o];
#pragma unroll
    for (int rr = 0; rr < 4; rr++) {
      int i = i0 + w * 16 + l4 * 4 + rr;
      float v = fmaxf(fmaf(acc[nb][rr] + bs, sc, bo_), 0.f);
      size_t oidx = ((size_t)n * LEN + i) * 128 + o;
      if (OUTF) Yf[oidx] = v;
      else Yb[oidx] = f2bf(v);
    }
  }
}

__global__ void avgpool2_bf(const unsigned short* __restrict__ x,
                            unsigned short* __restrict__ y, int nI, int nTot4)
{
  int j = blockIdx.x * 256 + threadIdx.x;
  if (j >= nTot4) return;
  int cq = j & 31;
  int i = (j >> 5) % nI;
  int n = j / (nI * 32);
  const ushort4* a = (const ushort4*)&x[(((size_t)n * nI + i) * 2) * 128 + cq * 4];
  const ushort4* b = (const ushort4*)&x[(((size_t)n * nI + i) * 2 + 1) * 128 + cq * 4];
  ushort4 ua = *a, ub = *b;
  ushort4 r;
  r.x = f2bf(0.5f * (bf2f(ua.x) + bf2f(ub.x)));
  r.y = f2bf(0.5f * (bf2f(ua.y) + bf2f(ub.y)));
  r.z = f2bf(0.5f * (bf2f(ua.z) + bf2f(ub.z)));
  r.w = f2bf(0.5f * (bf2f(ua.w) + bf2f(ub.w)));
  ((ushort4*)y)[j] = r;
}

// pool (pairs along L) + transpose to flat order [n][c*128+i], bf16 out for fc1 MFMA.
__global__ void pool3_transpose_bf(const float* __restrict__ x,
                                   unsigned short* __restrict__ y)
{
  int j = blockIdx.x * 256 + threadIdx.x;   // n*16384 + c*128 + i
  if (j >= 524288) return;
  int i = j & 127, c = (j >> 7) & 127, n = j >> 14;
  const float* b = x + ((size_t)n * 256 + 2 * i) * 128 + c;
  y[j] = f2bf(0.5f * (b[0] + b[128]));
}

// fc1 split-K MFMA: X [32][16384] bf16 @ W [256][16384] bf16 -> pt[64][32][256] f32.
// grid = 128 blocks (2 o-tiles x 64 K-groups of 256); W read exactly once.
__global__ __launch_bounds__(256) void fc1_mfma(
    const unsigned short* __restrict__ X, const unsigned short* __restrict__ WB,
    float* __restrict__ pt)
{
  const int tid = threadIdx.x;
  const int w = tid >> 6, lane = tid & 63;
  const int l15 = lane & 15, l4 = lane >> 4;
  const int ot = blockIdx.x & 1;
  const int kg = blockIdx.x >> 1;      // 0..63
  const int k0 = kg * 256;

  f32x4 acc[2][2] = {};                // [m-frag][nb]
  for (int kk = 0; kk < 256; kk += 32) {
    bf16x8 a0 = *(const bf16x8*)&X[(size_t)l15 * 16384 + k0 + kk + l4 * 8];
    bf16x8 a1 = *(const bf16x8*)&X[(size_t)(16 + l15) * 16384 + k0 + kk + l4 * 8];
#pragma unroll
    for (int nb = 0; nb < 2; nb++) {
      int o = ot * 128 + w * 32 + nb * 16 + l15;
      bf16x8 b = *(const bf16x8*)&WB[(size_t)o * 16384 + k0 + kk + l4 * 8];
      acc[0][nb] = __builtin_amdgcn_mfma_f32_16x16x32_bf16(a0, b, acc[0][nb], 0, 0, 0);
      acc[1][nb] = __builtin_amdgcn_mfma_f32_16x16x32_bf16(a1, b, acc[1][nb], 0, 0, 0);
    }
  }
#pragma unroll
  for (int mf = 0; mf < 2; mf++)
#pragma unroll
    for (int nb = 0; nb < 2; nb++) {
      int o = ot * 128 + w * 32 + nb * 16 + l15;
#pragma unroll
      for (int r = 0; r < 4; r++) {
        int n = mf * 16 + l4 * 4 + r;
        pt[((size_t)kg * 32 + n) * 256 + o] = acc[mf][nb][r];
      }
    }
}

// reduce partials + bias + relu + bn -> f1 [32][256] f32
__global__ __launch_bounds__(256) void fc1_reduce(
    const float* __restrict__ pt, const float* __restrict__ bias,
    const float* __restrict__ g, const float* __restrict__ bb,
    float* __restrict__ y)
{
  int o = threadIdx.x, n = blockIdx.x;
  float s = 0.f;
  for (int kg = 0; kg < 64; kg++) s += pt[((size_t)kg * 32 + n) * 256 + o];
  s += bias[o];
  s = fmaxf(s, 0.f);
  y[n * 256 + o] = fmaf(s, g[o] * rsqrtf(1.f + 1e-5f), bb[o]);
}

__global__ __launch_bounds__(256) void fc2_kernel(
    const float* __restrict__ x, const float* __restrict__ W,
    const float* __restrict__ bias, const float* __restrict__ g,
    const float* __restrict__ bb, float* __restrict__ y)
{
  int o = blockIdx.x & 127, n = blockIdx.x >> 7;
  float s = x[n * 256 + threadIdx.x] * W[o * 256 + threadIdx.x];
  s = wave_sum64(s);
  __shared__ float red[4];
  if ((threadIdx.x & 63) == 0) red[threadIdx.x >> 6] = s;
  __syncthreads();
  if (threadIdx.x == 0) {
    float v = red[0] + red[1] + red[2] + red[3] + bias[o];
    v = fmaxf(v, 0.f);
    y[n * 128 + o] = fmaf(v, g[o] * rsqrtf(1.f + 1e-5f), bb[o]);
  }
}

__global__ __launch_bounds__(64) void fc3_kernel(
    const float* __restrict__ x, const float* __restrict__ W,
    const float* __restrict__ bias, float* __restrict__ out)
{
  int n = threadIdx.x;
  if (n < 32) {
    float s = bias[0];
    for (int k = 0; k < 128; k++) s = fmaf(x[n * 128 + k], W[k], s);
    float p = 1.f / (1.f + expf(-s));
    out[n] = p;
    out[32 + n] = (p >= 0.5f) ? 1.f : 0.f;
  }
}

extern "C" void kernel_launch(void* const* d_in, const int* in_sizes, int n_in,
                              void* d_out, int out_size, void* d_ws, size_t ws_size,
                              hipStream_t stream)
{
  const float* datas = (const float*)d_in[0];
  const float* Wqkv = (const float*)d_in[6];
  const float* bqkv = (const float*)d_in[7];
  const float* Wo   = (const float*)d_in[8];
  const float* bo   = (const float*)d_in[9];
  const float* ln1g = (const float*)d_in[10];
  const float* ln1b = (const float*)d_in[11];
  const float* W1   = (const float*)d_in[12];
  const float* b1   = (const float*)d_in[13];
  const float* W2   = (const float*)d_in[14];
  const float* b2   = (const float*)d_in[15];
  const float* ln2g = (const float*)d_in[16];
  const float* ln2b = (const float*)d_in[17];
  const float* Wv1  = (const float*)d_in[18];
  const float* bv1  = (const float*)d_in[19];
  const float* Wu1  = (const float*)d_in[20];
  const float* bu1  = (const float*)d_in[21];
  const float* Ww1  = (const float*)d_in[22];
  const float* bw1  = (const float*)d_in[23];
  const float* Wv2  = (const float*)d_in[24];
  const float* bv2  = (const float*)d_in[25];
  const float* Wu2  = (const float*)d_in[26];
  const float* bu2  = (const float*)d_in[27];
  const float* Ww2  = (const float*)d_in[28];
  const float* bw2  = (const float*)d_in[29];
  const float* Kc1  = (const float*)d_in[30];
  const float* bc1  = (const float*)d_in[31];
  const float* gc1  = (const float*)d_in[32];
  const float* bb1  = (const float*)d_in[33];
  const float* Kc2  = (const float*)d_in[34];
  const float* bc2  = (const float*)d_in[35];
  const float* gc2  = (const float*)d_in[36];
  const float* bb2  = (const float*)d_in[37];
  const float* Kc3  = (const float*)d_in[38];
  const float* bc3  = (const float*)d_in[39];
  const float* gc3  = (const float*)d_in[40];
  const float* bb3  = (const float*)d_in[41];
  const float* Wf1  = (const float*)d_in[42];
  const float* bf1  = (const float*)d_in[43];
  const float* g4   = (const float*)d_in[44];
  const float* b4   = (const float*)d_in[45];
  const float* Wf2  = (const float*)d_in[46];
  const float* bf2  = (const float*)d_in[47];
  const float* g5   = (const float*)d_in[48];
  const float* b5   = (const float*)d_in[49];
  const float* Wf3  = (const float*)d_in[50];
  const float* bf3  = (const float*)d_in[51];

  float* ws = (float*)d_ws;
  float* h_f32 = ws;                              // 2,097,152 f
  float* R2f   = ws + 2097152;                    // 6,291,456 f
  unsigned short* h_bf = (unsigned short*)(ws + 8388608);   // 2,097,152 ush
  unsigned short* wbuf = (unsigned short*)(ws + 9437184);   // 3,473,408 ush
  float* biasG = ws + 11173888;                   // 256 f
  unsigned short* VTg = (unsigned short*)(ws + 11174144);   // 2,097,152 ush (V^T [512][4096])

  unsigned short* qkv_bf = (unsigned short*)R2f;
  unsigned short* O_bf   = (unsigned short*)(R2f + 3145728);
  unsigned short* ff1_bf = (unsigned short*)R2f;
  float* projf = R2f + 4194304;

  unsigned short* WqkvB = wbuf;                 // 786,432 (per-layer reuse)
  unsigned short* WoB   = wbuf + 786432;        // 262,144
  unsigned short* W1B   = wbuf + 1048576;       // 1,048,576
  unsigned short* W2B   = wbuf + 2097152;       // 1,048,576
  unsigned short* WvuB  = wbuf + 3145728;       // 131,072 (persistent tail)
  unsigned short* Wr2B  = wbuf + 3276800;       // 81,920
  unsigned short* Wr3B  = wbuf + 3358720;       // 114,688

  // Wf1B overlays h_f32 (dead after seg_pool stage 1); 4,194,304 ush = 2M f exactly.
  unsigned short* Wf1B = (unsigned short*)h_f32;

  float* out_f = (float*)d_out;

  init_h<<<2048, 256, 0, stream>>>(datas, h_f32, h_bf, 524288);
  reorder_w<<<320, 256, 0, stream>>>(Kc2, Wr2B, 5, 81920);
  reorder_w<<<448, 256, 0, stream>>>(Kc3, Wr3B, 7, 114688);
  hipMemcpyAsync(biasG, bv1, 128 * sizeof(float), hipMemcpyDeviceToDevice, stream);
  hipMemcpyAsync(biasG + 128, bu1, 128 * sizeof(float), hipMemcpyDeviceToDevice, stream);

  for (int l = 0; l < 2; l++) {
    CastJobs J{};
    J.src[0] = Wqkv + (size_t)l * 786432;  J.dst[0] = WqkvB; J.n4[0] = 196608;
    J.src[1] = Wo   + (size_t)l * 262144;  J.dst[1] = WoB;   J.n4[1] = 65536;
    J.src[2] = W1   + (size_t)l * 1048576; J.dst[2] = W1B;   J.n4[2] = 262144;
    J.src[3] = W2   + (size_t)l * 1048576; J.dst[3] = W2B;   J.n4[3] = 262144;
    J.njobs = 4;
    if (l == 0) {
      J.src[4] = Wv1; J.dst[4] = WvuB;         J.n4[4] = 16384;
      J.src[5] = Wu1; J.dst[5] = WvuB + 65536; J.n4[5] = 16384;
      J.njobs = 6;
    }
    cast_multi<<<512, 256, 0, stream>>>(J);

    // qkv: Q,K -> qkv_bf [t][1536]; V -> VTg [h*64+d][t]
    mgemm<0, 1, 1><<<dim3(12, 32), 256, 0, stream>>>(
        h_bf, WqkvB, bqkv + (size_t)l * 1536, nullptr, qkv_bf, VTg, 4096, 1536, 512);
    attn_mfma<<<dim3(64, 8), 256, 0, stream>>>(qkv_bf, VTg, O_bf);
    mgemm<0, 0, 0><<<dim3(4, 32), 256, 0, stream>>>(
        O_bf, WoB, bo + (size_t)l * 512, projf, nullptr, nullptr, 4096, 512, 512);
    residual_ln<<<4096, 64, 0, stream>>>(projf, h_f32, ln1g + l * 512, ln1b + l * 512,
                                         h_f32, h_bf);
    mgemm<1, 1, 0><<<dim3(16, 32), 256, 0, stream>>>(
        h_bf, W1B, b1 + (size_t)l * 2048, nullptr, ff1_bf, nullptr, 4096, 2048, 512);
    mgemm<0, 0, 0><<<dim3(4, 32), 256, 0, stream>>>(
        ff1_bf, W2B, b2 + (size_t)l * 512, projf, nullptr, nullptr, 4096, 512, 2048);
    residual_ln<<<4096, 64, 0, stream>>>(projf, h_f32, ln2g + l * 512, ln2b + l * 512,
                                         h_f32, h_bf);
  }

  // ---- gated pooling (stage 1: fused tanh/sigmoid GEMM, N=256) ----
  float* G    = R2f;              // 4096 x 256
  float* A1   = R2f + 1048576;
  float* out1 = R2f + 1052672;
  float* Gv2  = R2f + 1183744;
  float* Gu2  = R2f + 1216512;
  float* A2   = R2f + 1249280;
  float* out2 = R2f + 1249536;

  mgemm<4, 0, 0><<<dim3(2, 32), 256, 0, stream>>>(
      h_bf, WvuB, biasG, G, nullptr, nullptr, 4096, 256, 512);
  gate_dot<<<4096, 128, 0, stream>>>(G, G + 128, 256, Ww1, bw1, A1);
  seg_pool<<<256, 256, 0, stream>>>(A1, h_f32, out_f + 64, out1, 16);

  // h_f32 is dead now -> cast Wf1 into its storage (stream-ordered after seg_pool)
  {
    CastJobs J{};
    J.src[0] = Wf1; J.dst[0] = Wf1B; J.n4[0] = 1048576;
    J.njobs = 1;
    cast_multi<<<512, 256, 0, stream>>>(J);
  }

  gemm_bias<2><<<dim3(2, 4), 256, 0, stream>>>(out1, Wv2, bv2, Gv2, 256, 128, 512);
  gemm_bias<3><<<dim3(2, 4), 256, 0, stream>>>(out1, Wu2, bu2, Gu2, 256, 128, 512);
  gate_dot<<<256, 128, 0, stream>>>(Gv2, Gu2, 128, Ww2, bw2, A2);
  seg_pool<<<32, 256, 0, stream>>>(A2, out1, out_f + 4160, out2, 8);

  // ---- CNN head, channels-last ----
  unsigned short* c1T = (unsigned short*)(R2f + 1310720);  // 2,097,152 ush
  unsigned short* c2T = (unsigned short*)(R2f + 2359296);  // 2,097,152 ush
  unsigned short* p2T = (unsigned short*)(R2f + 3407872);  // 1,048,576 ush
  float* c3T = R2f + 3932160;                              // 1,048,576 f
  unsigned short* p3B = (unsigned short*)(R2f + 4980736);  // 524,288 ush (262,144 f)
  float* pt  = R2f + 5242880;                              // 524,288 f
  float* f1  = R2f + 5767168;                              // 8,192 f
  float* f2  = R2f + 5775360;                              // 4,096 f

  conv1_bnT<<<8192, 256, 0, stream>>>(out2, Kc1, bc1, gc1, bb1, c1T);
  convT_mfma<5, 2, 512, 0><<<dim3(16, 32), 256, 0, stream>>>(
      c1T, Wr2B, bc2, gc2, bb2, c2T, nullptr);
  avgpool2_bf<<<1024, 256, 0, stream>>>(c2T, p2T, 256, 262144);
  convT_mfma<7, 3, 256, 1><<<dim3(8, 32), 256, 0, stream>>>(
      p2T, Wr3B, bc3, gc3, bb3, nullptr, c3T);
  pool3_transpose_bf<<<2048, 256, 0, stream>>>(c3T, p3B);
  fc1_mfma<<<128, 256, 0, stream>>>(p3B, Wf1B, pt);
  fc1_reduce<<<32, 256, 0, stream>>>(pt, bf1, g4, b4, f1);
  fc2_kernel<<<4096, 256, 0, stream>>>(f1, Wf2, bf2, g5, b5, f2);
  fc3_kernel<<<1, 64, 0, stream>>>(f2, Wf3, bf3, out_f);
}

// Round 13
// 583.763 us; speedup vs baseline: 1.1374x; 1.0188x over previous
//
#include <hip/hip_runtime.h>
#include <math.h>

// T=4096, M=512, NH=8, HD=64, FF=2048, NL=2, NI=256 (16 tok/seg), NO=32 (8 seg/outer)

typedef float f32x4 __attribute__((ext_vector_type(4)));
typedef __bf16 bf16x8 __attribute__((ext_vector_type(8)));

__device__ __forceinline__ unsigned short f2bf(float x) {
  unsigned int u = __builtin_bit_cast(unsigned int, x);
  u += 0x7FFFu + ((u >> 16) & 1u);
  return (unsigned short)(u >> 16);
}
__device__ __forceinline__ float bf2f(unsigned short u) {
  unsigned int x = ((unsigned int)u) << 16;
  return __builtin_bit_cast(float, x);
}
// pack two f32 -> two bf16 (RTNE) in one instruction
__device__ __forceinline__ unsigned int pk_bf16(float a, float b) {
  unsigned int r;
  asm("v_cvt_pk_bf16_f32 %0, %1, %2" : "=v"(r) : "v"(a), "v"(b));
  return r;
}

__device__ __forceinline__ float wave_sum64(float v) {
#pragma unroll
  for (int o = 32; o > 0; o >>= 1) v += __shfl_xor(v, o);
  return v;
}

// XOR swizzle for LDS tiles with 128-byte rows (64 bf16/row).
__device__ __forceinline__ int swz(int byte) {
  return byte ^ (((byte >> 7) & 7) << 4);
}
// XOR swizzle for LDS tiles with 256-byte rows (128 bf16/row).
__device__ __forceinline__ int swz256(int byte) {
  return byte ^ (((byte >> 8) & 7) << 4);
}

// ============ bf16 MFMA GEMM (reg-staged, swizzled, software prefetch) ============
// ACT: 0 none, 1 relu, 2 tanh, 3 sigmoid, 4 col<128?tanh:sigmoid (fused gate)
// VSPLIT: cols >= 1024 go to VT[col-1024][row] (bf16, packed 4-row stores).
template<int ACT, int OUTBF, int VSPLIT>
__global__ __launch_bounds__(256) void mgemm(
    const unsigned short* __restrict__ A, const unsigned short* __restrict__ B,
    const float* __restrict__ bias, float* __restrict__ Cf,
    unsigned short* __restrict__ Cb, unsigned short* __restrict__ VT,
    int M, int N, int K)
{
  __shared__ __align__(16) unsigned short As[128 * 64];
  __shared__ __align__(16) unsigned short Bs[128 * 64];
  const int tid = threadIdx.x;
  const int wid = tid >> 6, lane = tid & 63;
  const int wm = wid >> 1, wn = wid & 1;
  const int l15 = lane & 15, l4 = lane >> 4;
  const int m0 = blockIdx.y * 128, n0 = blockIdx.x * 128;
  const int srow = tid >> 3;
  const int scol = (tid & 7) * 8;

  f32x4 acc[4][4] = {};

  bf16x8 ra[4], rb[4];
#pragma unroll
  for (int i = 0; i < 4; i++) {
    ra[i] = *(const bf16x8*)&A[(size_t)(m0 + srow + i * 32) * K + scol];
    rb[i] = *(const bf16x8*)&B[(size_t)(n0 + srow + i * 32) * K + scol];
  }

  for (int k0 = 0; k0 < K; k0 += 64) {
    __syncthreads();   // all waves done reading previous LDS tile
#pragma unroll
    for (int i = 0; i < 4; i++) {
      int byte = (srow + i * 32) * 128 + scol * 2;
      *(bf16x8*)((char*)As + swz(byte)) = ra[i];
      *(bf16x8*)((char*)Bs + swz(byte)) = rb[i];
    }
    __syncthreads();   // LDS ready
    if (k0 + 64 < K) { // prefetch next tile; latency hides under MFMA below
#pragma unroll
      for (int i = 0; i < 4; i++) {
        ra[i] = *(const bf16x8*)&A[(size_t)(m0 + srow + i * 32) * K + k0 + 64 + scol];
        rb[i] = *(const bf16x8*)&B[(size_t)(n0 + srow + i * 32) * K + k0 + 64 + scol];
      }
    }
#pragma unroll
    for (int kc = 0; kc < 2; kc++) {
      bf16x8 af[4], bf_[4];
#pragma unroll
      for (int i = 0; i < 4; i++) {
        int byteA = (wm * 64 + i * 16 + l15) * 128 + kc * 64 + l4 * 16;
        af[i] = *(const bf16x8*)((const char*)As + swz(byteA));
        int byteB = (wn * 64 + i * 16 + l15) * 128 + kc * 64 + l4 * 16;
        bf_[i] = *(const bf16x8*)((const char*)Bs + swz(byteB));
      }
#pragma unroll
      for (int i = 0; i < 4; i++)
#pragma unroll
        for (int j = 0; j < 4; j++)
          acc[i][j] = __builtin_amdgcn_mfma_f32_16x16x32_bf16(af[i], bf_[j], acc[i][j], 0, 0, 0);
    }
  }
#pragma unroll
  for (int i = 0; i < 4; i++) {
#pragma unroll
    for (int j = 0; j < 4; j++) {
      int col = n0 + wn * 64 + j * 16 + l15;
      float bv = bias[col];
      if (VSPLIT && col >= 1024) {
        float x0 = acc[i][j][0] + bv, x1 = acc[i][j][1] + bv;
        float x2 = acc[i][j][2] + bv, x3 = acc[i][j][3] + bv;
        uint2 pv;
        pv.x = pk_bf16(x0, x1);
        pv.y = pk_bf16(x2, x3);
        int row0 = m0 + wm * 64 + i * 16 + l4 * 4;
        *(uint2*)&VT[(size_t)(col - 1024) * 4096 + row0] = pv;
      } else {
#pragma unroll
        for (int r = 0; r < 4; r++) {
          int row = m0 + wm * 64 + i * 16 + l4 * 4 + r;
          float x = acc[i][j][r] + bv;
          if (ACT == 1) x = fmaxf(x, 0.f);
          if (ACT == 2) x = tanhf(x);
          if (ACT == 3) x = 1.f / (1.f + expf(-x));
          if (ACT == 4) x = (col < 128) ? tanhf(x) : (1.f / (1.f + expf(-x)));
          if (OUTBF) Cb[(size_t)row * N + col] = f2bf(x);
          else       Cf[(size_t)row * N + col] = x;
        }
      }
    }
  }
}

// ============ MFMA flash attention (round-9 numerics; + XCD-aware block remap) ============
// T1: h = id&7 pins all 64 same-head blocks to one XCD (id%8 round-robin), so the
// head's 1 MB K/V + VT slice is L2-resident instead of being re-served by L3.
// Bijective remap (id = qt*8 + h); per-block work bit-identical.
__global__ __launch_bounds__(256) void attn_mfma(
    const unsigned short* __restrict__ qkv, const unsigned short* __restrict__ VT,
    unsigned short* __restrict__ O)
{
  __shared__ __align__(16) unsigned short Ks[64 * 64];   // [k][d]   swizzled
  __shared__ __align__(16) unsigned short VTs[64 * 64];  // [d][k]   swizzled
  __shared__ __align__(16) unsigned short Ps[64 * 64];   // [q][k]   swizzled
  const int tid = threadIdx.x;
  const int w = tid >> 6, lane = tid & 63;
  const int l15 = lane & 15, l4 = lane >> 4;
  const int id = blockIdx.x + (int)gridDim.x * blockIdx.y;
  const int h = id & 7;          // XCD-pinned head
  const int qt = id >> 3;        // 0..63
  const float C = 0.18033688011112042f;   // 0.125 * log2(e)

  bf16x8 qf[2];
#pragma unroll
  for (int kc = 0; kc < 2; kc++)
    qf[kc] = *(const bf16x8*)&qkv[(size_t)(qt * 64 + w * 16 + l15) * 1536 + h * 64 + kc * 32 + l4 * 8];

  f32x4 oaccT[4] = {};
  float m = -1e30f, l = 0.f;

  const int sr = tid >> 3;
  const int sc = (tid & 7) * 8;
  const int vd = tid >> 2;            // 0..63
  const int vk0 = (tid & 3) * 16;     // 0,16,32,48

  const unsigned short* kp0 = qkv + (size_t)sr * 1536 + 512 + h * 64 + sc;
  const unsigned short* kp1 = kp0 + 32 * 1536;
  const unsigned short* vp = VT + (size_t)(h * 64 + vd) * 4096 + vk0;

  bf16x8 rk0 = *(const bf16x8*)kp0;
  bf16x8 rk1 = *(const bf16x8*)kp1;
  bf16x8 rv0 = *(const bf16x8*)vp;
  bf16x8 rv1 = *(const bf16x8*)(vp + 8);

  for (int kt = 0; kt < 64; kt++) {
    __syncthreads();   // previous tile fully consumed
    {
      int b0 = sr * 128 + sc * 2;
      *(bf16x8*)((char*)Ks + swz(b0)) = rk0;
      int b1 = (sr + 32) * 128 + sc * 2;
      *(bf16x8*)((char*)Ks + swz(b1)) = rk1;
      int vb0 = vd * 128 + vk0 * 2;
      *(bf16x8*)((char*)VTs + swz(vb0)) = rv0;
      *(bf16x8*)((char*)VTs + swz(vb0 + 16)) = rv1;
    }
    __syncthreads();   // LDS ready
    if (kt < 63) {     // prefetch next tile (bit-exact; hides HBM latency)
      kp0 += 64 * 1536; kp1 += 64 * 1536; vp += 64;
      rk0 = *(const bf16x8*)kp0;
      rk1 = *(const bf16x8*)kp1;
      rv0 = *(const bf16x8*)vp;
      rv1 = *(const bf16x8*)(vp + 8);
    }

    // S^T = mfma(A=K, B=Q)
    f32x4 st[4] = {};
    __builtin_amdgcn_s_setprio(1);
#pragma unroll
    for (int kc = 0; kc < 2; kc++) {
#pragma unroll
      for (int nb = 0; nb < 4; nb++) {
        int byte = (nb * 16 + l15) * 128 + kc * 64 + l4 * 16;
        bf16x8 kf = *(const bf16x8*)((const char*)Ks + swz(byte));
        st[nb] = __builtin_amdgcn_mfma_f32_16x16x32_bf16(kf, qf[kc], st[nb], 0, 0, 0);
      }
    }
    __builtin_amdgcn_s_setprio(0);

    // lane-local online softmax (always rescale)
    float tm = -1e30f;
#pragma unroll
    for (int nb = 0; nb < 4; nb++)
#pragma unroll
      for (int r = 0; r < 4; r++) tm = fmaxf(tm, st[nb][r]);
    tm = fmaxf(tm, __shfl_xor(tm, 16));
    tm = fmaxf(tm, __shfl_xor(tm, 32));
    float mn = fmaxf(m, tm);
    float alpha = exp2f((m - mn) * C);
    float e[4][4];
    float ps = 0.f;
#pragma unroll
    for (int nb = 0; nb < 4; nb++)
#pragma unroll
      for (int r = 0; r < 4; r++) {
        e[nb][r] = exp2f((st[nb][r] - mn) * C);
        ps += e[nb][r];
      }
    ps += __shfl_xor(ps, 16);
    ps += __shfl_xor(ps, 32);
    l = l * alpha + ps;
    m = mn;
#pragma unroll
    for (int nb = 0; nb < 4; nb++) oaccT[nb] *= alpha;

    // P rows -> Ps[q][k]
#pragma unroll
    for (int nb = 0; nb < 4; nb++) {
      uint2 pr;
      pr.x = pk_bf16(e[nb][0], e[nb][1]);
      pr.y = pk_bf16(e[nb][2], e[nb][3]);
      int byte = (w * 16 + l15) * 128 + (nb * 16 + l4 * 4) * 2;
      *(uint2*)((char*)Ps + swz(byte)) = pr;
    }

    // O^T += mfma(A=V^T, B=P)
#pragma unroll
    for (int kc = 0; kc < 2; kc++) {
      int bp = (w * 16 + l15) * 128 + kc * 64 + l4 * 16;
      bf16x8 pb = *(const bf16x8*)((const char*)Ps + swz(bp));
      __builtin_amdgcn_s_setprio(1);
#pragma unroll
      for (int nb = 0; nb < 4; nb++) {
        int bv = (nb * 16 + l15) * 128 + kc * 64 + l4 * 16;
        bf16x8 vf = *(const bf16x8*)((const char*)VTs + swz(bv));
        oaccT[nb] = __builtin_amdgcn_mfma_f32_16x16x32_bf16(vf, pb, oaccT[nb], 0, 0, 0);
      }
      __builtin_amdgcn_s_setprio(0);
    }
  }

  float linv = 1.f / l;
  int row = qt * 64 + w * 16 + l15;
#pragma unroll
  for (int nb = 0; nb < 4; nb++) {
    uint2 ov;
    ov.x = pk_bf16(oaccT[nb][0] * linv, oaccT[nb][1] * linv);
    ov.y = pk_bf16(oaccT[nb][2] * linv, oaccT[nb][3] * linv);
    int col = h * 64 + nb * 16 + l4 * 4;
    *(uint2*)&O[(size_t)row * 512 + col] = ov;
  }
}

// ---------------- fp32 GEMM (tiny stage-2 gating) ----------------
template<int ACT>
__global__ __launch_bounds__(256) void gemm_bias(
    const float* __restrict__ A, const float* __restrict__ B,
    const float* __restrict__ bias, float* __restrict__ C,
    int M, int N, int K)
{
  __shared__ float As[16][68];
  __shared__ float Bs[16][68];
  const int tid = threadIdx.x;
  const int tx = tid & 15, ty = tid >> 4;
  const int m0 = blockIdx.y * 64, n0 = blockIdx.x * 64;
  const int lr = tid >> 2;
  const int lk = (tid & 3) * 4;
  float acc[4][4] = {};
  for (int k0 = 0; k0 < K; k0 += 16) {
    __syncthreads();
    float4 av = *(const float4*)&A[(size_t)(m0 + lr) * K + k0 + lk];
    float4 bv = *(const float4*)&B[(size_t)(n0 + lr) * K + k0 + lk];
    As[lk + 0][lr] = av.x; As[lk + 1][lr] = av.y; As[lk + 2][lr] = av.z; As[lk + 3][lr] = av.w;
    Bs[lk + 0][lr] = bv.x; Bs[lk + 1][lr] = bv.y; Bs[lk + 2][lr] = bv.z; Bs[lk + 3][lr] = bv.w;
    __syncthreads();
#pragma unroll
    for (int k = 0; k < 16; k++) {
      float a[4], b[4];
#pragma unroll
      for (int i = 0; i < 4; i++) a[i] = As[k][ty * 4 + i];
#pragma unroll
      for (int j = 0; j < 4; j++) b[j] = Bs[k][tx * 4 + j];
#pragma unroll
      for (int i = 0; i < 4; i++)
#pragma unroll
        for (int j = 0; j < 4; j++)
          acc[i][j] = fmaf(a[i], b[j], acc[i][j]);
    }
  }
#pragma unroll
  for (int i = 0; i < 4; i++)
#pragma unroll
    for (int j = 0; j < 4; j++) {
      float x = acc[i][j] + bias[n0 + tx * 4 + j];
      if (ACT == 1) x = fmaxf(x, 0.f);
      if (ACT == 2) x = tanhf(x);
      if (ACT == 3) x = 1.f / (1.f + expf(-x));
      C[(size_t)(m0 + ty * 4 + i) * N + n0 + tx * 4 + j] = x;
    }
}

// ---------------- LayerNorm(x + res), writes f32 + bf16 ----------------
__global__ __launch_bounds__(64) void residual_ln(
    const float* __restrict__ x, const float* __restrict__ res,
    const float* __restrict__ g, const float* __restrict__ b,
    float* __restrict__ out, unsigned short* __restrict__ out_bf)
{
  const int row = blockIdx.x, lane = threadIdx.x;
  const float* xp = x + (size_t)row * 512;
  const float* rp = res + (size_t)row * 512;
  float v[8];
  float s = 0.f;
#pragma unroll
  for (int i = 0; i < 8; i++) { v[i] = xp[lane + 64 * i] + rp[lane + 64 * i]; s += v[i]; }
  s = wave_sum64(s);
  float mu = s * (1.f / 512.f);
  float vs = 0.f;
#pragma unroll
  for (int i = 0; i < 8; i++) { float d = v[i] - mu; vs = fmaf(d, d, vs); }
  vs = wave_sum64(vs);
  float rstd = rsqrtf(vs * (1.f / 512.f) + 1e-5f);
  float* op = out + (size_t)row * 512;
  unsigned short* ob = out_bf + (size_t)row * 512;
#pragma unroll
  for (int i = 0; i < 8; i++) {
    float y = (v[i] - mu) * rstd * g[lane + 64 * i] + b[lane + 64 * i];
    op[lane + 64 * i] = y;
    ob[lane + 64 * i] = f2bf(y);
  }
}

// ---------------- multi-job f32 -> bf16 cast (one launch per batch) ----------------
struct CastJobs {
  const float* src[6];
  unsigned short* dst[6];
  int n4[6];
  int njobs;
};

__global__ void cast_multi(CastJobs J)
{
  for (int j = 0; j < J.njobs; j++) {
    const float4* s = (const float4*)J.src[j];
    ushort4* d = (ushort4*)J.dst[j];
    int n = J.n4[j];
    for (int i = blockIdx.x * 256 + threadIdx.x; i < n; i += gridDim.x * 256) {
      float4 v = s[i];
      ushort4 u;
      u.x = f2bf(v.x); u.y = f2bf(v.y); u.z = f2bf(v.z); u.w = f2bf(v.w);
      d[i] = u;
    }
  }
}

__global__ void init_h(const float* __restrict__ in, float* __restrict__ hf,
                       unsigned short* __restrict__ hb, int n4)
{
  int i = blockIdx.x * 256 + threadIdx.x;
  if (i < n4) {
    float4 v = ((const float4*)in)[i];
    ((float4*)hf)[i] = v;
    ushort4 u;
    u.x = f2bf(v.x); u.y = f2bf(v.y); u.z = f2bf(v.z); u.w = f2bf(v.w);
    ((ushort4*)hb)[i] = u;
  }
}

// ---------------- A[t] = sum_l Gv*Gu*Ww + bw ----------------
__global__ __launch_bounds__(128) void gate_dot(
    const float* __restrict__ Gv, const float* __restrict__ Gu, int ld,
    const float* __restrict__ Ww, const float* __restrict__ bw,
    float* __restrict__ A)
{
  const int t = blockIdx.x, l = threadIdx.x;
  float v = Gv[(size_t)t * ld + l] * Gu[(size_t)t * ld + l] * Ww[l];
  v = wave_sum64(v);
  __shared__ float red[2];
  if ((l & 63) == 0) red[l >> 6] = v;
  __syncthreads();
  if (l == 0) A[t] = red[0] + red[1] + bw[0];
}

// ------- contiguous-segment softmax + weighted pooled sum (D=512) -------
__global__ __launch_bounds__(256) void seg_pool(
    const float* __restrict__ A, const float* __restrict__ X,
    float* __restrict__ w_out, float* __restrict__ out, int seg_len)
{
  const int s = blockIdx.x, tid = threadIdx.x;
  __shared__ float ws[16];
  if (tid < 64) {
    float a = (tid < seg_len) ? A[s * seg_len + tid] : -1e30f;
    float mx = a;
#pragma unroll
    for (int o = 1; o < 16; o <<= 1) mx = fmaxf(mx, __shfl_xor(mx, o));
    float e = (tid < seg_len) ? expf(a - mx) : 0.f;
    float se = e;
#pragma unroll
    for (int o = 1; o < 16; o <<= 1) se += __shfl_xor(se, o);
    if (tid < seg_len) {
      float w = e / se;
      ws[tid] = w;
      w_out[s * seg_len + tid] = w;
    }
  }
  __syncthreads();
  for (int d = tid; d < 512; d += 256) {
    float acc = 0.f;
    for (int i = 0; i < seg_len; i++)
      acc = fmaf(ws[i], X[(size_t)(s * seg_len + i) * 512 + d], acc);
    out[(size_t)s * 512 + d] = acc;
  }
}

// ======================= CNN head (channels-last [n][L][C=128]) =======================

__global__ void conv1_bnT(
    const float* __restrict__ x, const float* __restrict__ K4,
    const float* __restrict__ bias, const float* __restrict__ g,
    const float* __restrict__ bb, unsigned short* __restrict__ y)
{
  int idx = blockIdx.x * 256 + threadIdx.x;   // (n*512+i)*128+o
  int o = idx & 127, i = (idx >> 7) & 511, n = idx >> 16;
  const float* xp = x + n * 512;
  float acc = bias[o];
#pragma unroll
  for (int k = 0; k < 4; k++) {
    int p = i + k - 1;
    float xv = (p >= 0 && p < 512) ? xp[p] : 0.f;
    acc = fmaf(xv, K4[o * 4 + k], acc);
  }
  float sc = g[o] * rsqrtf(1.f + 1e-5f);
  y[idx] = f2bf(fmaxf(fmaf(acc, sc, bb[o]), 0.f));
}

__global__ void reorder_w(const float* __restrict__ Kc, unsigned short* __restrict__ Wr,
                          int KS, int total)
{
  int idx = blockIdx.x * 256 + threadIdx.x;
  if (idx < total) {
    int c = idx & 127;
    int kk = (idx >> 7) % KS;
    int o = idx / (128 * KS);
    Wr[idx] = f2bf(Kc[(o * 128 + c) * KS + kk]);
  }
}

template<int KS, int PAD, int LEN, int OUTF>
__global__ __launch_bounds__(256) void convT_mfma(
    const unsigned short* __restrict__ X, const unsigned short* __restrict__ Wr,
    const float* __restrict__ bias, const float* __restrict__ g,
    const float* __restrict__ bb,
    unsigned short* __restrict__ Yb, float* __restrict__ Yf)
{
  constexpr int ROWS = 64 + KS - 1;
  __shared__ __align__(16) unsigned short XT[ROWS * 128];
  const int tid = threadIdx.x;
  const int w = tid >> 6, lane = tid & 63;
  const int l15 = lane & 15, l4 = lane >> 4;
  const int i0 = (blockIdx.x >> 1) * 64;
  const int o0 = (blockIdx.x & 1) * 64;
  const int n = blockIdx.y;

  {
    const int c = (tid & 15) * 8;
    for (int r = tid >> 4; r < ROWS; r += 16) {
      int gi = i0 - PAD + r;
      bf16x8 v = {};
      if (gi >= 0 && gi < LEN)
        v = *(const bf16x8*)&X[((size_t)n * LEN + gi) * 128 + c];
      int byte = r * 256 + c * 2;
      *(bf16x8*)((char*)XT + swz256(byte)) = v;
    }
  }
  __syncthreads();

  f32x4 acc[4] = {};
#pragma unroll
  for (int kk = 0; kk < KS; kk++) {
#pragma unroll
    for (int cc = 0; cc < 4; cc++) {
      int r = w * 16 + l15 + kk;
      int byte = r * 256 + cc * 64 + l4 * 16;
      bf16x8 a = *(const bf16x8*)((const char*)XT + swz256(byte));
      bf16x8 bfr[4];
#pragma unroll
      for (int nb = 0; nb < 4; nb++)
        bfr[nb] = *(const bf16x8*)&Wr[(size_t)(o0 + nb * 16 + l15) * (KS * 128) +
                                      kk * 128 + cc * 32 + l4 * 8];
#pragma unroll
      for (int nb = 0; nb < 4; nb++)
        acc[nb] = __builtin_amdgcn_mfma_f32_16x16x32_bf16(a, bfr[nb], acc[nb], 0, 0, 0);
    }
  }

#pragma unroll
  for (int nb = 0; nb < 4; nb++) {
    int o = o0 + nb * 16 + l15;
    float sc = g[o] * rsqrtf(1.f + 1e-5f);
    float bs = bias[o], bo_ = bb[o];
#pragma unroll
    for (int rr = 0; rr < 4; rr++) {
      int i = i0 + w * 16 + l4 * 4 + rr;
      float v = fmaxf(fmaf(acc[nb][rr] + bs, sc, bo_), 0.f);
      size_t oidx = ((size_t)n * LEN + i) * 128 + o;
      if (OUTF) Yf[oidx] = v;
      else Yb[oidx] = f2bf(v);
    }
  }
}

__global__ void avgpool2_bf(const unsigned short* __restrict__ x,
                            unsigned short* __restrict__ y, int nI, int nTot4)
{
  int j = blockIdx.x * 256 + threadIdx.x;
  if (j >= nTot4) return;
  int cq = j & 31;
  int i = (j >> 5) % nI;
  int n = j / (nI * 32);
  const ushort4* a = (const ushort4*)&x[(((size_t)n * nI + i) * 2) * 128 + cq * 4];
  const ushort4* b = (const ushort4*)&x[(((size_t)n * nI + i) * 2 + 1) * 128 + cq * 4];
  ushort4 ua = *a, ub = *b;
  ushort4 r;
  r.x = f2bf(0.5f * (bf2f(ua.x) + bf2f(ub.x)));
  r.y = f2bf(0.5f * (bf2f(ua.y) + bf2f(ub.y)));
  r.z = f2bf(0.5f * (bf2f(ua.z) + bf2f(ub.z)));
  r.w = f2bf(0.5f * (bf2f(ua.w) + bf2f(ub.w)));
  ((ushort4*)y)[j] = r;
}

// pool (pairs along L) + transpose to flat order [n][c*128+i], bf16 out for fc1 MFMA.
__global__ void pool3_transpose_bf(const float* __restrict__ x,
                                   unsigned short* __restrict__ y)
{
  int j = blockIdx.x * 256 + threadIdx.x;   // n*16384 + c*128 + i
  if (j >= 524288) return;
  int i = j & 127, c = (j >> 7) & 127, n = j >> 14;
  const float* b = x + ((size_t)n * 256 + 2 * i) * 128 + c;
  y[j] = f2bf(0.5f * (b[0] + b[128]));
}

// fc1 split-K MFMA: X [32][16384] bf16 @ W [256][16384] bf16 -> pt[64][32][256] f32.
__global__ __launch_bounds__(256) void fc1_mfma(
    const unsigned short* __restrict__ X, const unsigned short* __restrict__ WB,
    float* __restrict__ pt)
{
  const int tid = threadIdx.x;
  const int w = tid >> 6, lane = tid & 63;
  const int l15 = lane & 15, l4 = lane >> 4;
  const int ot = blockIdx.x & 1;
  const int kg = blockIdx.x >> 1;      // 0..63
  const int k0 = kg * 256;

  f32x4 acc[2][2] = {};                // [m-frag][nb]
  for (int kk = 0; kk < 256; kk += 32) {
    bf16x8 a0 = *(const bf16x8*)&X[(size_t)l15 * 16384 + k0 + kk + l4 * 8];
    bf16x8 a1 = *(const bf16x8*)&X[(size_t)(16 + l15) * 16384 + k0 + kk + l4 * 8];
#pragma unroll
    for (int nb = 0; nb < 2; nb++) {
      int o = ot * 128 + w * 32 + nb * 16 + l15;
      bf16x8 b = *(const bf16x8*)&WB[(size_t)o * 16384 + k0 + kk + l4 * 8];
      acc[0][nb] = __builtin_amdgcn_mfma_f32_16x16x32_bf16(a0, b, acc[0][nb], 0, 0, 0);
      acc[1][nb] = __builtin_amdgcn_mfma_f32_16x16x32_bf16(a1, b, acc[1][nb], 0, 0, 0);
    }
  }
#pragma unroll
  for (int mf = 0; mf < 2; mf++)
#pragma unroll
    for (int nb = 0; nb < 2; nb++) {
      int o = ot * 128 + w * 32 + nb * 16 + l15;
#pragma unroll
      for (int r = 0; r < 4; r++) {
        int n = mf * 16 + l4 * 4 + r;
        pt[((size_t)kg * 32 + n) * 256 + o] = acc[mf][nb][r];
      }
    }
}

// reduce partials + bias + relu + bn -> f1 [32][256] f32
__global__ __launch_bounds__(256) void fc1_reduce(
    const float* __restrict__ pt, const float* __restrict__ bias,
    const float* __restrict__ g, const float* __restrict__ bb,
    float* __restrict__ y)
{
  int o = threadIdx.x, n = blockIdx.x;
  float s = 0.f;
  for (int kg = 0; kg < 64; kg++) s += pt[((size_t)kg * 32 + n) * 256 + o];
  s += bias[o];
  s = fmaxf(s, 0.f);
  y[n * 256 + o] = fmaf(s, g[o] * rsqrtf(1.f + 1e-5f), bb[o]);
}

__global__ __launch_bounds__(256) void fc2_kernel(
    const float* __restrict__ x, const float* __restrict__ W,
    const float* __restrict__ bias, const float* __restrict__ g,
    const float* __restrict__ bb, float* __restrict__ y)
{
  int o = blockIdx.x & 127, n = blockIdx.x >> 7;
  float s = x[n * 256 + threadIdx.x] * W[o * 256 + threadIdx.x];
  s = wave_sum64(s);
  __shared__ float red[4];
  if ((threadIdx.x & 63) == 0) red[threadIdx.x >> 6] = s;
  __syncthreads();
  if (threadIdx.x == 0) {
    float v = red[0] + red[1] + red[2] + red[3] + bias[o];
    v = fmaxf(v, 0.f);
    y[n * 128 + o] = fmaf(v, g[o] * rsqrtf(1.f + 1e-5f), bb[o]);
  }
}

__global__ __launch_bounds__(64) void fc3_kernel(
    const float* __restrict__ x, const float* __restrict__ W,
    const float* __restrict__ bias, float* __restrict__ out)
{
  int n = threadIdx.x;
  if (n < 32) {
    float s = bias[0];
    for (int k = 0; k < 128; k++) s = fmaf(x[n * 128 + k], W[k], s);
    float p = 1.f / (1.f + expf(-s));
    out[n] = p;
    out[32 + n] = (p >= 0.5f) ? 1.f : 0.f;
  }
}

extern "C" void kernel_launch(void* const* d_in, const int* in_sizes, int n_in,
                              void* d_out, int out_size, void* d_ws, size_t ws_size,
                              hipStream_t stream)
{
  const float* datas = (const float*)d_in[0];
  const float* Wqkv = (const float*)d_in[6];
  const float* bqkv = (const float*)d_in[7];
  const float* Wo   = (const float*)d_in[8];
  const float* bo   = (const float*)d_in[9];
  const float* ln1g = (const float*)d_in[10];
  const float* ln1b = (const float*)d_in[11];
  const float* W1   = (const float*)d_in[12];
  const float* b1   = (const float*)d_in[13];
  const float* W2   = (const float*)d_in[14];
  const float* b2   = (const float*)d_in[15];
  const float* ln2g = (const float*)d_in[16];
  const float* ln2b = (const float*)d_in[17];
  const float* Wv1  = (const float*)d_in[18];
  const float* bv1  = (const float*)d_in[19];
  const float* Wu1  = (const float*)d_in[20];
  const float* bu1  = (const float*)d_in[21];
  const float* Ww1  = (const float*)d_in[22];
  const float* bw1  = (const float*)d_in[23];
  const float* Wv2  = (const float*)d_in[24];
  const float* bv2  = (const float*)d_in[25];
  const float* Wu2  = (const float*)d_in[26];
  const float* bu2  = (const float*)d_in[27];
  const float* Ww2  = (const float*)d_in[28];
  const float* bw2  = (const float*)d_in[29];
  const float* Kc1  = (const float*)d_in[30];
  const float* bc1  = (const float*)d_in[31];
  const float* gc1  = (const float*)d_in[32];
  const float* bb1  = (const float*)d_in[33];
  const float* Kc2  = (const float*)d_in[34];
  const float* bc2  = (const float*)d_in[35];
  const float* gc2  = (const float*)d_in[36];
  const float* bb2  = (const float*)d_in[37];
  const float* Kc3  = (const float*)d_in[38];
  const float* bc3  = (const float*)d_in[39];
  const float* gc3  = (const float*)d_in[40];
  const float* bb3  = (const float*)d_in[41];
  const float* Wf1  = (const float*)d_in[42];
  const float* bf1  = (const float*)d_in[43];
  const float* g4   = (const float*)d_in[44];
  const float* b4   = (const float*)d_in[45];
  const float* Wf2  = (const float*)d_in[46];
  const float* bf2  = (const float*)d_in[47];
  const float* g5   = (const float*)d_in[48];
  const float* b5   = (const float*)d_in[49];
  const float* Wf3  = (const float*)d_in[50];
  const float* bf3  = (const float*)d_in[51];

  float* ws = (float*)d_ws;
  float* h_f32 = ws;                              // 2,097,152 f
  float* R2f   = ws + 2097152;                    // 6,291,456 f
  unsigned short* h_bf = (unsigned short*)(ws + 8388608);   // 2,097,152 ush
  unsigned short* wbuf = (unsigned short*)(ws + 9437184);   // 3,473,408 ush
  float* biasG = ws + 11173888;                   // 256 f
  unsigned short* VTg = (unsigned short*)(ws + 11174144);   // 2,097,152 ush (V^T [512][4096])

  unsigned short* qkv_bf = (unsigned short*)R2f;
  unsigned short* O_bf   = (unsigned short*)(R2f + 3145728);
  unsigned short* ff1_bf = (unsigned short*)R2f;
  float* projf = R2f + 4194304;

  unsigned short* WqkvB = wbuf;                 // 786,432 (per-layer reuse)
  unsigned short* WoB   = wbuf + 786432;        // 262,144
  unsigned short* W1B   = wbuf + 1048576;       // 1,048,576
  unsigned short* W2B   = wbuf + 2097152;       // 1,048,576
  unsigned short* WvuB  = wbuf + 3145728;       // 131,072 (persistent tail)
  unsigned short* Wr2B  = wbuf + 3276800;       // 81,920
  unsigned short* Wr3B  = wbuf + 3358720;       // 114,688

  // Wf1B overlays h_f32 (dead after seg_pool stage 1); 4,194,304 ush = 2M f exactly.
  unsigned short* Wf1B = (unsigned short*)h_f32;

  float* out_f = (float*)d_out;

  init_h<<<2048, 256, 0, stream>>>(datas, h_f32, h_bf, 524288);
  reorder_w<<<320, 256, 0, stream>>>(Kc2, Wr2B, 5, 81920);
  reorder_w<<<448, 256, 0, stream>>>(Kc3, Wr3B, 7, 114688);
  hipMemcpyAsync(biasG, bv1, 128 * sizeof(float), hipMemcpyDeviceToDevice, stream);
  hipMemcpyAsync(biasG + 128, bu1, 128 * sizeof(float), hipMemcpyDeviceToDevice, stream);

  for (int l = 0; l < 2; l++) {
    CastJobs J{};
    J.src[0] = Wqkv + (size_t)l * 786432;  J.dst[0] = WqkvB; J.n4[0] = 196608;
    J.src[1] = Wo   + (size_t)l * 262144;  J.dst[1] = WoB;   J.n4[1] = 65536;
    J.src[2] = W1   + (size_t)l * 1048576; J.dst[2] = W1B;   J.n4[2] = 262144;
    J.src[3] = W2   + (size_t)l * 1048576; J.dst[3] = W2B;   J.n4[3] = 262144;
    J.njobs = 4;
    if (l == 0) {
      J.src[4] = Wv1; J.dst[4] = WvuB;         J.n4[4] = 16384;
      J.src[5] = Wu1; J.dst[5] = WvuB + 65536; J.n4[5] = 16384;
      J.njobs = 6;
    }
    cast_multi<<<512, 256, 0, stream>>>(J);

    // qkv: Q,K -> qkv_bf [t][1536]; V -> VTg [h*64+d][t]
    mgemm<0, 1, 1><<<dim3(12, 32), 256, 0, stream>>>(
        h_bf, WqkvB, bqkv + (size_t)l * 1536, nullptr, qkv_bf, VTg, 4096, 1536, 512);
    attn_mfma<<<dim3(64, 8), 256, 0, stream>>>(qkv_bf, VTg, O_bf);
    mgemm<0, 0, 0><<<dim3(4, 32), 256, 0, stream>>>(
        O_bf, WoB, bo + (size_t)l * 512, projf, nullptr, nullptr, 4096, 512, 512);
    residual_ln<<<4096, 64, 0, stream>>>(projf, h_f32, ln1g + l * 512, ln1b + l * 512,
                                         h_f32, h_bf);
    mgemm<1, 1, 0><<<dim3(16, 32), 256, 0, stream>>>(
        h_bf, W1B, b1 + (size_t)l * 2048, nullptr, ff1_bf, nullptr, 4096, 2048, 512);
    mgemm<0, 0, 0><<<dim3(4, 32), 256, 0, stream>>>(
        ff1_bf, W2B, b2 + (size_t)l * 512, projf, nullptr, nullptr, 4096, 512, 2048);
    residual_ln<<<4096, 64, 0, stream>>>(projf, h_f32, ln2g + l * 512, ln2b + l * 512,
                                         h_f32, h_bf);
  }

  // ---- gated pooling (stage 1: fused tanh/sigmoid GEMM, N=256) ----
  float* G    = R2f;              // 4096 x 256
  float* A1   = R2f + 1048576;
  float* out1 = R2f + 1052672;
  float* Gv2  = R2f + 1183744;
  float* Gu2  = R2f + 1216512;
  float* A2   = R2f + 1249280;
  float* out2 = R2f + 1249536;

  mgemm<4, 0, 0><<<dim3(2, 32), 256, 0, stream>>>(
      h_bf, WvuB, biasG, G, nullptr, nullptr, 4096, 256, 512);
  gate_dot<<<4096, 128, 0, stream>>>(G, G + 128, 256, Ww1, bw1, A1);
  seg_pool<<<256, 256, 0, stream>>>(A1, h_f32, out_f + 64, out1, 16);

  // h_f32 is dead now -> cast Wf1 into its storage (stream-ordered after seg_pool)
  {
    CastJobs J{};
    J.src[0] = Wf1; J.dst[0] = Wf1B; J.n4[0] = 1048576;
    J.njobs = 1;
    cast_multi<<<512, 256, 0, stream>>>(J);
  }

  gemm_bias<2><<<dim3(2, 4), 256, 0, stream>>>(out1, Wv2, bv2, Gv2, 256, 128, 512);
  gemm_bias<3><<<dim3(2, 4), 256, 0, stream>>>(out1, Wu2, bu2, Gu2, 256, 128, 512);
  gate_dot<<<256, 128, 0, stream>>>(Gv2, Gu2, 128, Ww2, bw2, A2);
  seg_pool<<<32, 256, 0, stream>>>(A2, out1, out_f + 4160, out2, 8);

  // ---- CNN head, channels-last ----
  unsigned short* c1T = (unsigned short*)(R2f + 1310720);  // 2,097,152 ush
  unsigned short* c2T = (unsigned short*)(R2f + 2359296);  // 2,097,152 ush
  unsigned short* p2T = (unsigned short*)(R2f + 3407872);  // 1,048,576 ush
  float* c3T = R2f + 3932160;                              // 1,048,576 f
  unsigned short* p3B = (unsigned short*)(R2f + 4980736);  // 524,288 ush (262,144 f)
  float* pt  = R2f + 5242880;                              // 524,288 f
  float* f1  = R2f + 5767168;                              // 8,192 f
  float* f2  = R2f + 5775360;                              // 4,096 f

  conv1_bnT<<<8192, 256, 0, stream>>>(out2, Kc1, bc1, gc1, bb1, c1T);
  convT_mfma<5, 2, 512, 0><<<dim3(16, 32), 256, 0, stream>>>(
      c1T, Wr2B, bc2, gc2, bb2, c2T, nullptr);
  avgpool2_bf<<<1024, 256, 0, stream>>>(c2T, p2T, 256, 262144);
  convT_mfma<7, 3, 256, 1><<<dim3(8, 32), 256, 0, stream>>>(
      p2T, Wr3B, bc3, gc3, bb3, nullptr, c3T);
  pool3_transpose_bf<<<2048, 256, 0, stream>>>(c3T, p3B);
  fc1_mfma<<<128, 256, 0, stream>>>(p3B, Wf1B, pt);
  fc1_reduce<<<32, 256, 0, stream>>>(pt, bf1, g4, b4, f1);
  fc2_kernel<<<4096, 256, 0, stream>>>(f1, Wf2, bf2, g5, b5, f2);
  fc3_kernel<<<1, 64, 0, stream>>>(f2, Wf3, bf3, out_f);
}

// Round 14
// 561.829 us; speedup vs baseline: 1.1818x; 1.0390x over previous
//
#include <hip/hip_runtime.h>
#include <math.h>

// T=4096, M=512, NH=8, HD=64, FF=2048, NL=2, NI=256 (16 tok/seg), NO=32 (8 seg/outer)

typedef float f32x4 __attribute__((ext_vector_type(4)));
typedef __bf16 bf16x8 __attribute__((ext_vector_type(8)));

__device__ __forceinline__ unsigned short f2bf(float x) {
  unsigned int u = __builtin_bit_cast(unsigned int, x);
  u += 0x7FFFu + ((u >> 16) & 1u);
  return (unsigned short)(u >> 16);
}
__device__ __forceinline__ float bf2f(unsigned short u) {
  unsigned int x = ((unsigned int)u) << 16;
  return __builtin_bit_cast(float, x);
}
// pack two f32 -> two bf16 (RTNE) in one instruction
__device__ __forceinline__ unsigned int pk_bf16(float a, float b) {
  unsigned int r;
  asm("v_cvt_pk_bf16_f32 %0, %1, %2" : "=v"(r) : "v"(a), "v"(b));
  return r;
}

__device__ __forceinline__ float wave_sum64(float v) {
#pragma unroll
  for (int o = 32; o > 0; o >>= 1) v += __shfl_xor(v, o);
  return v;
}

// XOR swizzle for LDS tiles with 128-byte rows (64 bf16/row).
__device__ __forceinline__ int swz(int byte) {
  return byte ^ (((byte >> 7) & 7) << 4);
}
// XOR swizzle for LDS tiles with 256-byte rows (128 bf16/row).
__device__ __forceinline__ int swz256(int byte) {
  return byte ^ (((byte >> 8) & 7) << 4);
}

// ============ bf16 MFMA GEMM (reg-staged, swizzled, software prefetch) ============
// __launch_bounds__(256,2): grids here are <=512 blocks (<=2/CU, 8 waves/CU =
// 2/SIMD), so allow 256 VGPRs -> compiler keeps addresses/staging in registers.
template<int ACT, int OUTBF, int VSPLIT>
__global__ __launch_bounds__(256, 2) void mgemm(
    const unsigned short* __restrict__ A, const unsigned short* __restrict__ B,
    const float* __restrict__ bias, float* __restrict__ Cf,
    unsigned short* __restrict__ Cb, unsigned short* __restrict__ VT,
    int M, int N, int K)
{
  __shared__ __align__(16) unsigned short As[128 * 64];
  __shared__ __align__(16) unsigned short Bs[128 * 64];
  const int tid = threadIdx.x;
  const int wid = tid >> 6, lane = tid & 63;
  const int wm = wid >> 1, wn = wid & 1;
  const int l15 = lane & 15, l4 = lane >> 4;
  const int m0 = blockIdx.y * 128, n0 = blockIdx.x * 128;
  const int srow = tid >> 3;
  const int scol = (tid & 7) * 8;

  f32x4 acc[4][4] = {};

  bf16x8 ra[4], rb[4];
#pragma unroll
  for (int i = 0; i < 4; i++) {
    ra[i] = *(const bf16x8*)&A[(size_t)(m0 + srow + i * 32) * K + scol];
    rb[i] = *(const bf16x8*)&B[(size_t)(n0 + srow + i * 32) * K + scol];
  }

  for (int k0 = 0; k0 < K; k0 += 64) {
    __syncthreads();   // all waves done reading previous LDS tile
#pragma unroll
    for (int i = 0; i < 4; i++) {
      int byte = (srow + i * 32) * 128 + scol * 2;
      *(bf16x8*)((char*)As + swz(byte)) = ra[i];
      *(bf16x8*)((char*)Bs + swz(byte)) = rb[i];
    }
    __syncthreads();   // LDS ready
    if (k0 + 64 < K) { // prefetch next tile; latency hides under MFMA below
#pragma unroll
      for (int i = 0; i < 4; i++) {
        ra[i] = *(const bf16x8*)&A[(size_t)(m0 + srow + i * 32) * K + k0 + 64 + scol];
        rb[i] = *(const bf16x8*)&B[(size_t)(n0 + srow + i * 32) * K + k0 + 64 + scol];
      }
    }
#pragma unroll
    for (int kc = 0; kc < 2; kc++) {
      bf16x8 af[4], bf_[4];
#pragma unroll
      for (int i = 0; i < 4; i++) {
        int byteA = (wm * 64 + i * 16 + l15) * 128 + kc * 64 + l4 * 16;
        af[i] = *(const bf16x8*)((const char*)As + swz(byteA));
        int byteB = (wn * 64 + i * 16 + l15) * 128 + kc * 64 + l4 * 16;
        bf_[i] = *(const bf16x8*)((const char*)Bs + swz(byteB));
      }
#pragma unroll
      for (int i = 0; i < 4; i++)
#pragma unroll
        for (int j = 0; j < 4; j++)
          acc[i][j] = __builtin_amdgcn_mfma_f32_16x16x32_bf16(af[i], bf_[j], acc[i][j], 0, 0, 0);
    }
  }
#pragma unroll
  for (int i = 0; i < 4; i++) {
#pragma unroll
    for (int j = 0; j < 4; j++) {
      int col = n0 + wn * 64 + j * 16 + l15;
      float bv = bias[col];
      if (VSPLIT && col >= 1024) {
        float x0 = acc[i][j][0] + bv, x1 = acc[i][j][1] + bv;
        float x2 = acc[i][j][2] + bv, x3 = acc[i][j][3] + bv;
        uint2 pv;
        pv.x = pk_bf16(x0, x1);
        pv.y = pk_bf16(x2, x3);
        int row0 = m0 + wm * 64 + i * 16 + l4 * 4;
        *(uint2*)&VT[(size_t)(col - 1024) * 4096 + row0] = pv;
      } else {
#pragma unroll
        for (int r = 0; r < 4; r++) {
          int row = m0 + wm * 64 + i * 16 + l4 * 4 + r;
          float x = acc[i][j][r] + bv;
          if (ACT == 1) x = fmaxf(x, 0.f);
          if (ACT == 2) x = tanhf(x);
          if (ACT == 3) x = 1.f / (1.f + expf(-x));
          if (ACT == 4) x = (col < 128) ? tanhf(x) : (1.f / (1.f + expf(-x)));
          if (OUTBF) Cb[(size_t)row * N + col] = f2bf(x);
          else       Cf[(size_t)row * N + col] = x;
        }
      }
    }
  }
}

// ============ MFMA flash attention ============
// Round-13 numerics (bit-exact) + XCD remap. NEW: __launch_bounds__(256,2) (grid
// is 2 blocks/CU -> allow 256 VGPRs) and ALL swizzled LDS addresses hoisted out
// of the 64-iteration kt loop into registers (they are kt-invariant; at 60 VGPRs
// the compiler was rematerializing them every iteration -> inflated VALUBusy).
__global__ __launch_bounds__(256, 2) void attn_mfma(
    const unsigned short* __restrict__ qkv, const unsigned short* __restrict__ VT,
    unsigned short* __restrict__ O)
{
  __shared__ __align__(16) unsigned short Ks[64 * 64];   // [k][d]   swizzled
  __shared__ __align__(16) unsigned short VTs[64 * 64];  // [d][k]   swizzled
  __shared__ __align__(16) unsigned short Ps[64 * 64];   // [q][k]   swizzled
  const int tid = threadIdx.x;
  const int w = tid >> 6, lane = tid & 63;
  const int l15 = lane & 15, l4 = lane >> 4;
  const int id = blockIdx.x + (int)gridDim.x * blockIdx.y;
  const int h = id & 7;          // XCD-pinned head
  const int qt = id >> 3;        // 0..63
  const float C = 0.18033688011112042f;   // 0.125 * log2(e)

  bf16x8 qf[2];
#pragma unroll
  for (int kc = 0; kc < 2; kc++)
    qf[kc] = *(const bf16x8*)&qkv[(size_t)(qt * 64 + w * 16 + l15) * 1536 + h * 64 + kc * 32 + l4 * 8];

  f32x4 oaccT[4] = {};
  float m = -1e30f, l = 0.f;

  const int sr = tid >> 3;
  const int sc = (tid & 7) * 8;
  const int vd = tid >> 2;            // 0..63
  const int vk0 = (tid & 3) * 16;     // 0,16,32,48

  // ---- hoisted, kt-invariant LDS byte offsets (stay in VGPRs) ----
  const int kw0 = swz(sr * 128 + sc * 2);              // Ks write row sr
  const int kw1 = swz((sr + 32) * 128 + sc * 2);       // Ks write row sr+32
  const int vw0 = swz(vd * 128 + vk0 * 2);             // VTs write
  const int vw1 = swz(vd * 128 + vk0 * 2 + 16);
  int rdA[2][4];                                       // Ks & VTs fragment reads
#pragma unroll
  for (int kc = 0; kc < 2; kc++)
#pragma unroll
    for (int nb = 0; nb < 4; nb++)
      rdA[kc][nb] = swz((nb * 16 + l15) * 128 + kc * 64 + l4 * 16);
  int pwA[4];                                          // Ps writes (own q-row)
#pragma unroll
  for (int nb = 0; nb < 4; nb++)
    pwA[nb] = swz((w * 16 + l15) * 128 + (nb * 16 + l4 * 4) * 2);
  int prA[2];                                          // Ps reads
#pragma unroll
  for (int kc = 0; kc < 2; kc++)
    prA[kc] = swz((w * 16 + l15) * 128 + kc * 64 + l4 * 16);

  const unsigned short* kp0 = qkv + (size_t)sr * 1536 + 512 + h * 64 + sc;
  const unsigned short* kp1 = kp0 + 32 * 1536;
  const unsigned short* vp = VT + (size_t)(h * 64 + vd) * 4096 + vk0;

  bf16x8 rk0 = *(const bf16x8*)kp0;
  bf16x8 rk1 = *(const bf16x8*)kp1;
  bf16x8 rv0 = *(const bf16x8*)vp;
  bf16x8 rv1 = *(const bf16x8*)(vp + 8);

  for (int kt = 0; kt < 64; kt++) {
    __syncthreads();   // previous tile fully consumed
    {
      *(bf16x8*)((char*)Ks + kw0) = rk0;
      *(bf16x8*)((char*)Ks + kw1) = rk1;
      *(bf16x8*)((char*)VTs + vw0) = rv0;
      *(bf16x8*)((char*)VTs + vw1) = rv1;
    }
    __syncthreads();   // LDS ready
    if (kt < 63) {     // prefetch next tile (bit-exact; hides HBM latency)
      kp0 += 64 * 1536; kp1 += 64 * 1536; vp += 64;
      rk0 = *(const bf16x8*)kp0;
      rk1 = *(const bf16x8*)kp1;
      rv0 = *(const bf16x8*)vp;
      rv1 = *(const bf16x8*)(vp + 8);
    }

    // S^T = mfma(A=K, B=Q)
    f32x4 st[4] = {};
    __builtin_amdgcn_s_setprio(1);
#pragma unroll
    for (int kc = 0; kc < 2; kc++) {
#pragma unroll
      for (int nb = 0; nb < 4; nb++) {
        bf16x8 kf = *(const bf16x8*)((const char*)Ks + rdA[kc][nb]);
        st[nb] = __builtin_amdgcn_mfma_f32_16x16x32_bf16(kf, qf[kc], st[nb], 0, 0, 0);
      }
    }
    __builtin_amdgcn_s_setprio(0);

    // lane-local online softmax (always rescale; round-3/8 exact numerics)
    float tm = -1e30f;
#pragma unroll
    for (int nb = 0; nb < 4; nb++)
#pragma unroll
      for (int r = 0; r < 4; r++) tm = fmaxf(tm, st[nb][r]);
    tm = fmaxf(tm, __shfl_xor(tm, 16));
    tm = fmaxf(tm, __shfl_xor(tm, 32));
    float mn = fmaxf(m, tm);
    float alpha = exp2f((m - mn) * C);
    float e[4][4];
    float ps = 0.f;
#pragma unroll
    for (int nb = 0; nb < 4; nb++)
#pragma unroll
      for (int r = 0; r < 4; r++) {
        e[nb][r] = exp2f((st[nb][r] - mn) * C);
        ps += e[nb][r];
      }
    ps += __shfl_xor(ps, 16);
    ps += __shfl_xor(ps, 32);
    l = l * alpha + ps;
    m = mn;
#pragma unroll
    for (int nb = 0; nb < 4; nb++) oaccT[nb] *= alpha;

    // P rows -> Ps[q][k] (lane writes its own q-row; wave-local, no barrier)
#pragma unroll
    for (int nb = 0; nb < 4; nb++) {
      uint2 pr;
      pr.x = pk_bf16(e[nb][0], e[nb][1]);
      pr.y = pk_bf16(e[nb][2], e[nb][3]);
      *(uint2*)((char*)Ps + pwA[nb]) = pr;
    }

    // O^T += mfma(A=V^T, B=P)
#pragma unroll
    for (int kc = 0; kc < 2; kc++) {
      bf16x8 pb = *(const bf16x8*)((const char*)Ps + prA[kc]);
      __builtin_amdgcn_s_setprio(1);
#pragma unroll
      for (int nb = 0; nb < 4; nb++) {
        bf16x8 vf = *(const bf16x8*)((const char*)VTs + rdA[kc][nb]);
        oaccT[nb] = __builtin_amdgcn_mfma_f32_16x16x32_bf16(vf, pb, oaccT[nb], 0, 0, 0);
      }
      __builtin_amdgcn_s_setprio(0);
    }
  }

  float linv = 1.f / l;
  int row = qt * 64 + w * 16 + l15;
#pragma unroll
  for (int nb = 0; nb < 4; nb++) {
    uint2 ov;
    ov.x = pk_bf16(oaccT[nb][0] * linv, oaccT[nb][1] * linv);
    ov.y = pk_bf16(oaccT[nb][2] * linv, oaccT[nb][3] * linv);
    int col = h * 64 + nb * 16 + l4 * 4;
    *(uint2*)&O[(size_t)row * 512 + col] = ov;
  }
}

// ---------------- fp32 GEMM (tiny stage-2 gating) ----------------
template<int ACT>
__global__ __launch_bounds__(256) void gemm_bias(
    const float* __restrict__ A, const float* __restrict__ B,
    const float* __restrict__ bias, float* __restrict__ C,
    int M, int N, int K)
{
  __shared__ float As[16][68];
  __shared__ float Bs[16][68];
  const int tid = threadIdx.x;
  const int tx = tid & 15, ty = tid >> 4;
  const int m0 = blockIdx.y * 64, n0 = blockIdx.x * 64;
  const int lr = tid >> 2;
  const int lk = (tid & 3) * 4;
  float acc[4][4] = {};
  for (int k0 = 0; k0 < K; k0 += 16) {
    __syncthreads();
    float4 av = *(const float4*)&A[(size_t)(m0 + lr) * K + k0 + lk];
    float4 bv = *(const float4*)&B[(size_t)(n0 + lr) * K + k0 + lk];
    As[lk + 0][lr] = av.x; As[lk + 1][lr] = av.y; As[lk + 2][lr] = av.z; As[lk + 3][lr] = av.w;
    Bs[lk + 0][lr] = bv.x; Bs[lk + 1][lr] = bv.y; Bs[lk + 2][lr] = bv.z; Bs[lk + 3][lr] = bv.w;
    __syncthreads();
#pragma unroll
    for (int k = 0; k < 16; k++) {
      float a[4], b[4];
#pragma unroll
      for (int i = 0; i < 4; i++) a[i] = As[k][ty * 4 + i];
#pragma unroll
      for (int j = 0; j < 4; j++) b[j] = Bs[k][tx * 4 + j];
#pragma unroll
      for (int i = 0; i < 4; i++)
#pragma unroll
        for (int j = 0; j < 4; j++)
          acc[i][j] = fmaf(a[i], b[j], acc[i][j]);
    }
  }
#pragma unroll
  for (int i = 0; i < 4; i++)
#pragma unroll
    for (int j = 0; j < 4; j++) {
      float x = acc[i][j] + bias[n0 + tx * 4 + j];
      if (ACT == 1) x = fmaxf(x, 0.f);
      if (ACT == 2) x = tanhf(x);
      if (ACT == 3) x = 1.f / (1.f + expf(-x));
      C[(size_t)(m0 + ty * 4 + i) * N + n0 + tx * 4 + j] = x;
    }
}

// ---------------- LayerNorm(x + res), writes f32 + bf16 ----------------
__global__ __launch_bounds__(64) void residual_ln(
    const float* __restrict__ x, const float* __restrict__ res,
    const float* __restrict__ g, const float* __restrict__ b,
    float* __restrict__ out, unsigned short* __restrict__ out_bf)
{
  const int row = blockIdx.x, lane = threadIdx.x;
  const float* xp = x + (size_t)row * 512;
  const float* rp = res + (size_t)row * 512;
  float v[8];
  float s = 0.f;
#pragma unroll
  for (int i = 0; i < 8; i++) { v[i] = xp[lane + 64 * i] + rp[lane + 64 * i]; s += v[i]; }
  s = wave_sum64(s);
  float mu = s * (1.f / 512.f);
  float vs = 0.f;
#pragma unroll
  for (int i = 0; i < 8; i++) { float d = v[i] - mu; vs = fmaf(d, d, vs); }
  vs = wave_sum64(vs);
  float rstd = rsqrtf(vs * (1.f / 512.f) + 1e-5f);
  float* op = out + (size_t)row * 512;
  unsigned short* ob = out_bf + (size_t)row * 512;
#pragma unroll
  for (int i = 0; i < 8; i++) {
    float y = (v[i] - mu) * rstd * g[lane + 64 * i] + b[lane + 64 * i];
    op[lane + 64 * i] = y;
    ob[lane + 64 * i] = f2bf(y);
  }
}

// ---------------- multi-job f32 -> bf16 cast (one launch per batch) ----------------
struct CastJobs {
  const float* src[6];
  unsigned short* dst[6];
  int n4[6];
  int njobs;
};

__global__ void cast_multi(CastJobs J)
{
  for (int j = 0; j < J.njobs; j++) {
    const float4* s = (const float4*)J.src[j];
    ushort4* d = (ushort4*)J.dst[j];
    int n = J.n4[j];
    for (int i = blockIdx.x * 256 + threadIdx.x; i < n; i += gridDim.x * 256) {
      float4 v = s[i];
      ushort4 u;
      u.x = f2bf(v.x); u.y = f2bf(v.y); u.z = f2bf(v.z); u.w = f2bf(v.w);
      d[i] = u;
    }
  }
}

__global__ void init_h(const float* __restrict__ in, float* __restrict__ hf,
                       unsigned short* __restrict__ hb, int n4)
{
  int i = blockIdx.x * 256 + threadIdx.x;
  if (i < n4) {
    float4 v = ((const float4*)in)[i];
    ((float4*)hf)[i] = v;
    ushort4 u;
    u.x = f2bf(v.x); u.y = f2bf(v.y); u.z = f2bf(v.z); u.w = f2bf(v.w);
    ((ushort4*)hb)[i] = u;
  }
}

// ---------------- A[t] = sum_l Gv*Gu*Ww + bw ----------------
__global__ __launch_bounds__(128) void gate_dot(
    const float* __restrict__ Gv, const float* __restrict__ Gu, int ld,
    const float* __restrict__ Ww, const float* __restrict__ bw,
    float* __restrict__ A)
{
  const int t = blockIdx.x, l = threadIdx.x;
  float v = Gv[(size_t)t * ld + l] * Gu[(size_t)t * ld + l] * Ww[l];
  v = wave_sum64(v);
  __shared__ float red[2];
  if ((l & 63) == 0) red[l >> 6] = v;
  __syncthreads();
  if (l == 0) A[t] = red[0] + red[1] + bw[0];
}

// ------- contiguous-segment softmax + weighted pooled sum (D=512) -------
__global__ __launch_bounds__(256) void seg_pool(
    const float* __restrict__ A, const float* __restrict__ X,
    float* __restrict__ w_out, float* __restrict__ out, int seg_len)
{
  const int s = blockIdx.x, tid = threadIdx.x;
  __shared__ float ws[16];
  if (tid < 64) {
    float a = (tid < seg_len) ? A[s * seg_len + tid] : -1e30f;
    float mx = a;
#pragma unroll
    for (int o = 1; o < 16; o <<= 1) mx = fmaxf(mx, __shfl_xor(mx, o));
    float e = (tid < seg_len) ? expf(a - mx) : 0.f;
    float se = e;
#pragma unroll
    for (int o = 1; o < 16; o <<= 1) se += __shfl_xor(se, o);
    if (tid < seg_len) {
      float w = e / se;
      ws[tid] = w;
      w_out[s * seg_len + tid] = w;
    }
  }
  __syncthreads();
  for (int d = tid; d < 512; d += 256) {
    float acc = 0.f;
    for (int i = 0; i < seg_len; i++)
      acc = fmaf(ws[i], X[(size_t)(s * seg_len + i) * 512 + d], acc);
    out[(size_t)s * 512 + d] = acc;
  }
}

// ======================= CNN head (channels-last [n][L][C=128]) =======================

__global__ void conv1_bnT(
    const float* __restrict__ x, const float* __restrict__ K4,
    const float* __restrict__ bias, const float* __restrict__ g,
    const float* __restrict__ bb, unsigned short* __restrict__ y)
{
  int idx = blockIdx.x * 256 + threadIdx.x;   // (n*512+i)*128+o
  int o = idx & 127, i = (idx >> 7) & 511, n = idx >> 16;
  const float* xp = x + n * 512;
  float acc = bias[o];
#pragma unroll
  for (int k = 0; k < 4; k++) {
    int p = i + k - 1;
    float xv = (p >= 0 && p < 512) ? xp[p] : 0.f;
    acc = fmaf(xv, K4[o * 4 + k], acc);
  }
  float sc = g[o] * rsqrtf(1.f + 1e-5f);
  y[idx] = f2bf(fmaxf(fmaf(acc, sc, bb[o]), 0.f));
}

__global__ void reorder_w(const float* __restrict__ Kc, unsigned short* __restrict__ Wr,
                          int KS, int total)
{
  int idx = blockIdx.x * 256 + threadIdx.x;
  if (idx < total) {
    int c = idx & 127;
    int kk = (idx >> 7) % KS;
    int o = idx / (128 * KS);
    Wr[idx] = f2bf(Kc[(o * 128 + c) * KS + kk]);
  }
}

template<int KS, int PAD, int LEN, int OUTF>
__global__ __launch_bounds__(256) void convT_mfma(
    const unsigned short* __restrict__ X, const unsigned short* __restrict__ Wr,
    const float* __restrict__ bias, const float* __restrict__ g,
    const float* __restrict__ bb,
    unsigned short* __restrict__ Yb, float* __restrict__ Yf)
{
  constexpr int ROWS = 64 + KS - 1;
  __shared__ __align__(16) unsigned short XT[ROWS * 128];
  const int tid = threadIdx.x;
  const int w = tid >> 6, lane = tid & 63;
  const int l15 = lane & 15, l4 = lane >> 4;
  const int i0 = (blockIdx.x >> 1) * 64;
  const int o0 = (blockIdx.x & 1) * 64;
  const int n = blockIdx.y;

  {
    const int c = (tid & 15) * 8;
    for (int r = tid >> 4; r < ROWS; r += 16) {
      int gi = i0 - PAD + r;
      bf16x8 v = {};
      if (gi >= 0 && gi < LEN)
        v = *(const bf16x8*)&X[((size_t)n * LEN + gi) * 128 + c];
      int byte = r * 256 + c * 2;
      *(bf16x8*)((char*)XT + swz256(byte)) = v;
    }
  }
  __syncthreads();

  f32x4 acc[4] = {};
#pragma unroll
  for (int kk = 0; kk < KS; kk++) {
#pragma unroll
    for (int cc = 0; cc < 4; cc++) {
      int r = w * 16 + l15 + kk;
      int byte = r * 256 + cc * 64 + l4 * 16;
      bf16x8 a = *(const bf16x8*)((const char*)XT + swz256(byte));
      bf16x8 bfr[4];
#pragma unroll
      for (int nb = 0; nb < 4; nb++)
        bfr[nb] = *(const bf16x8*)&Wr[(size_t)(o0 + nb * 16 + l15) * (KS * 128) +
                                      kk * 128 + cc * 32 + l4 * 8];
#pragma unroll
      for (int nb = 0; nb < 4; nb++)
        acc[nb] = __builtin_amdgcn_mfma_f32_16x16x32_bf16(a, bfr[nb], acc[nb], 0, 0, 0);
    }
  }

#pragma unroll
  for (int nb = 0; nb < 4; nb++) {
    int o = o0 + nb * 16 + l15;
    float sc = g[o] * rsqrtf(1.f + 1e-5f);
    float bs = bias[o], bo_ = bb[o];
#pragma unroll
    for (int rr = 0; rr < 4; rr++) {
      int i = i0 + w * 16 + l4 * 4 + rr;
      float v = fmaxf(fmaf(acc[nb][rr] + bs, sc, bo_), 0.f);
      size_t oidx = ((size_t)n * LEN + i) * 128 + o;
      if (OUTF) Yf[oidx] = v;
      else Yb[oidx] = f2bf(v);
    }
  }
}

__global__ void avgpool2_bf(const unsigned short* __restrict__ x,
                            unsigned short* __restrict__ y, int nI, int nTot4)
{
  int j = blockIdx.x * 256 + threadIdx.x;
  if (j >= nTot4) return;
  int cq = j & 31;
  int i = (j >> 5) % nI;
  int n = j / (nI * 32);
  const ushort4* a = (const ushort4*)&x[(((size_t)n * nI + i) * 2) * 128 + cq * 4];
  const ushort4* b = (const ushort4*)&x[(((size_t)n * nI + i) * 2 + 1) * 128 + cq * 4];
  ushort4 ua = *a, ub = *b;
  ushort4 r;
  r.x = f2bf(0.5f * (bf2f(ua.x) + bf2f(ub.x)));
  r.y = f2bf(0.5f * (bf2f(ua.y) + bf2f(ub.y)));
  r.z = f2bf(0.5f * (bf2f(ua.z) + bf2f(ub.z)));
  r.w = f2bf(0.5f * (bf2f(ua.w) + bf2f(ub.w)));
  ((ushort4*)y)[j] = r;
}

// pool (pairs along L) + transpose to flat order [n][c*128+i], bf16 out for fc1 MFMA.
__global__ void pool3_transpose_bf(const float* __restrict__ x,
                                   unsigned short* __restrict__ y)
{
  int j = blockIdx.x * 256 + threadIdx.x;   // n*16384 + c*128 + i
  if (j >= 524288) return;
  int i = j & 127, c = (j >> 7) & 127, n = j >> 14;
  const float* b = x + ((size_t)n * 256 + 2 * i) * 128 + c;
  y[j] = f2bf(0.5f * (b[0] + b[128]));
}

// fc1 split-K MFMA: X [32][16384] bf16 @ W [256][16384] bf16 -> pt[64][32][256] f32.
__global__ __launch_bounds__(256) void fc1_mfma(
    const unsigned short* __restrict__ X, const unsigned short* __restrict__ WB,
    float* __restrict__ pt)
{
  const int tid = threadIdx.x;
  const int w = tid >> 6, lane = tid & 63;
  const int l15 = lane & 15, l4 = lane >> 4;
  const int ot = blockIdx.x & 1;
  const int kg = blockIdx.x >> 1;      // 0..63
  const int k0 = kg * 256;

  f32x4 acc[2][2] = {};                // [m-frag][nb]
  for (int kk = 0; kk < 256; kk += 32) {
    bf16x8 a0 = *(const bf16x8*)&X[(size_t)l15 * 16384 + k0 + kk + l4 * 8];
    bf16x8 a1 = *(const bf16x8*)&X[(size_t)(16 + l15) * 16384 + k0 + kk + l4 * 8];
#pragma unroll
    for (int nb = 0; nb < 2; nb++) {
      int o = ot * 128 + w * 32 + nb * 16 + l15;
      bf16x8 b = *(const bf16x8*)&WB[(size_t)o * 16384 + k0 + kk + l4 * 8];
      acc[0][nb] = __builtin_amdgcn_mfma_f32_16x16x32_bf16(a0, b, acc[0][nb], 0, 0, 0);
      acc[1][nb] = __builtin_amdgcn_mfma_f32_16x16x32_bf16(a1, b, acc[1][nb], 0, 0, 0);
    }
  }
#pragma unroll
  for (int mf = 0; mf < 2; mf++)
#pragma unroll
    for (int nb = 0; nb < 2; nb++) {
      int o = ot * 128 + w * 32 + nb * 16 + l15;
#pragma unroll
      for (int r = 0; r < 4; r++) {
        int n = mf * 16 + l4 * 4 + r;
        pt[((size_t)kg * 32 + n) * 256 + o] = acc[mf][nb][r];
      }
    }
}

// reduce partials + bias + relu + bn -> f1 [32][256] f32
__global__ __launch_bounds__(256) void fc1_reduce(
    const float* __restrict__ pt, const float* __restrict__ bias,
    const float* __restrict__ g, const float* __restrict__ bb,
    float* __restrict__ y)
{
  int o = threadIdx.x, n = blockIdx.x;
  float s = 0.f;
  for (int kg = 0; kg < 64; kg++) s += pt[((size_t)kg * 32 + n) * 256 + o];
  s += bias[o];
  s = fmaxf(s, 0.f);
  y[n * 256 + o] = fmaf(s, g[o] * rsqrtf(1.f + 1e-5f), bb[o]);
}

__global__ __launch_bounds__(256) void fc2_kernel(
    const float* __restrict__ x, const float* __restrict__ W,
    const float* __restrict__ bias, const float* __restrict__ g,
    const float* __restrict__ bb, float* __restrict__ y)
{
  int o = blockIdx.x & 127, n = blockIdx.x >> 7;
  float s = x[n * 256 + threadIdx.x] * W[o * 256 + threadIdx.x];
  s = wave_sum64(s);
  __shared__ float red[4];
  if ((threadIdx.x & 63) == 0) red[threadIdx.x >> 6] = s;
  __syncthreads();
  if (threadIdx.x == 0) {
    float v = red[0] + red[1] + red[2] + red[3] + bias[o];
    v = fmaxf(v, 0.f);
    y[n * 128 + o] = fmaf(v, g[o] * rsqrtf(1.f + 1e-5f), bb[o]);
  }
}

__global__ __launch_bounds__(64) void fc3_kernel(
    const float* __restrict__ x, const float* __restrict__ W,
    const float* __restrict__ bias, float* __restrict__ out)
{
  int n = threadIdx.x;
  if (n < 32) {
    float s = bias[0];
    for (int k = 0; k < 128; k++) s = fmaf(x[n * 128 + k], W[k], s);
    float p = 1.f / (1.f + expf(-s));
    out[n] = p;
    out[32 + n] = (p >= 0.5f) ? 1.f : 0.f;
  }
}

extern "C" void kernel_launch(void* const* d_in, const int* in_sizes, int n_in,
                              void* d_out, int out_size, void* d_ws, size_t ws_size,
                              hipStream_t stream)
{
  const float* datas = (const float*)d_in[0];
  const float* Wqkv = (const float*)d_in[6];
  const float* bqkv = (const float*)d_in[7];
  const float* Wo   = (const float*)d_in[8];
  const float* bo   = (const float*)d_in[9];
  const float* ln1g = (const float*)d_in[10];
  const float* ln1b = (const float*)d_in[11];
  const float* W1   = (const float*)d_in[12];
  const float* b1   = (const float*)d_in[13];
  const float* W2   = (const float*)d_in[14];
  const float* b2   = (const float*)d_in[15];
  const float* ln2g = (const float*)d_in[16];
  const float* ln2b = (const float*)d_in[17];
  const float* Wv1  = (const float*)d_in[18];
  const float* bv1  = (const float*)d_in[19];
  const float* Wu1  = (const float*)d_in[20];
  const float* bu1  = (const float*)d_in[21];
  const float* Ww1  = (const float*)d_in[22];
  const float* bw1  = (const float*)d_in[23];
  const float* Wv2  = (const float*)d_in[24];
  const float* bv2  = (const float*)d_in[25];
  const float* Wu2  = (const float*)d_in[26];
  const float* bu2  = (const float*)d_in[27];
  const float* Ww2  = (const float*)d_in[28];
  const float* bw2  = (const float*)d_in[29];
  const float* Kc1  = (const float*)d_in[30];
  const float* bc1  = (const float*)d_in[31];
  const float* gc1  = (const float*)d_in[32];
  const float* bb1  = (const float*)d_in[33];
  const float* Kc2  = (const float*)d_in[34];
  const float* bc2  = (const float*)d_in[35];
  const float* gc2  = (const float*)d_in[36];
  const float* bb2  = (const float*)d_in[37];
  const float* Kc3  = (const float*)d_in[38];
  const float* bc3  = (const float*)d_in[39];
  const float* gc3  = (const float*)d_in[40];
  const float* bb3  = (const float*)d_in[41];
  const float* Wf1  = (const float*)d_in[42];
  const float* bf1  = (const float*)d_in[43];
  const float* g4   = (const float*)d_in[44];
  const float* b4   = (const float*)d_in[45];
  const float* Wf2  = (const float*)d_in[46];
  const float* bf2  = (const float*)d_in[47];
  const float* g5   = (const float*)d_in[48];
  const float* b5   = (const float*)d_in[49];
  const float* Wf3  = (const float*)d_in[50];
  const float* bf3  = (const float*)d_in[51];

  float* ws = (float*)d_ws;
  float* h_f32 = ws;                              // 2,097,152 f
  float* R2f   = ws + 2097152;                    // 6,291,456 f
  unsigned short* h_bf = (unsigned short*)(ws + 8388608);   // 2,097,152 ush
  unsigned short* wbuf = (unsigned short*)(ws + 9437184);   // 3,473,408 ush
  float* biasG = ws + 11173888;                   // 256 f
  unsigned short* VTg = (unsigned short*)(ws + 11174144);   // 2,097,152 ush (V^T [512][4096])

  unsigned short* qkv_bf = (unsigned short*)R2f;
  unsigned short* O_bf   = (unsigned short*)(R2f + 3145728);
  unsigned short* ff1_bf = (unsigned short*)R2f;
  float* projf = R2f + 4194304;

  unsigned short* WqkvB = wbuf;                 // 786,432 (per-layer reuse)
  unsigned short* WoB   = wbuf + 786432;        // 262,144
  unsigned short* W1B   = wbuf + 1048576;       // 1,048,576
  unsigned short* W2B   = wbuf + 2097152;       // 1,048,576
  unsigned short* WvuB  = wbuf + 3145728;       // 131,072 (persistent tail)
  unsigned short* Wr2B  = wbuf + 3276800;       // 81,920
  unsigned short* Wr3B  = wbuf + 3358720;       // 114,688

  // Wf1B overlays h_f32 (dead after seg_pool stage 1); 4,194,304 ush = 2M f exactly.
  unsigned short* Wf1B = (unsigned short*)h_f32;

  float* out_f = (float*)d_out;

  init_h<<<2048, 256, 0, stream>>>(datas, h_f32, h_bf, 524288);
  reorder_w<<<320, 256, 0, stream>>>(Kc2, Wr2B, 5, 81920);
  reorder_w<<<448, 256, 0, stream>>>(Kc3, Wr3B, 7, 114688);
  hipMemcpyAsync(biasG, bv1, 128 * sizeof(float), hipMemcpyDeviceToDevice, stream);
  hipMemcpyAsync(biasG + 128, bu1, 128 * sizeof(float), hipMemcpyDeviceToDevice, stream);

  for (int l = 0; l < 2; l++) {
    CastJobs J{};
    J.src[0] = Wqkv + (size_t)l * 786432;  J.dst[0] = WqkvB; J.n4[0] = 196608;
    J.src[1] = Wo   + (size_t)l * 262144;  J.dst[1] = WoB;   J.n4[1] = 65536;
    J.src[2] = W1   + (size_t)l * 1048576; J.dst[2] = W1B;   J.n4[2] = 262144;
    J.src[3] = W2   + (size_t)l * 1048576; J.dst[3] = W2B;   J.n4[3] = 262144;
    J.njobs = 4;
    if (l == 0) {
      J.src[4] = Wv1; J.dst[4] = WvuB;         J.n4[4] = 16384;
      J.src[5] = Wu1; J.dst[5] = WvuB + 65536; J.n4[5] = 16384;
      J.njobs = 6;
    }
    cast_multi<<<512, 256, 0, stream>>>(J);

    // qkv: Q,K -> qkv_bf [t][1536]; V -> VTg [h*64+d][t]
    mgemm<0, 1, 1><<<dim3(12, 32), 256, 0, stream>>>(
        h_bf, WqkvB, bqkv + (size_t)l * 1536, nullptr, qkv_bf, VTg, 4096, 1536, 512);
    attn_mfma<<<dim3(64, 8), 256, 0, stream>>>(qkv_bf, VTg, O_bf);
    mgemm<0, 0, 0><<<dim3(4, 32), 256, 0, stream>>>(
        O_bf, WoB, bo + (size_t)l * 512, projf, nullptr, nullptr, 4096, 512, 512);
    residual_ln<<<4096, 64, 0, stream>>>(projf, h_f32, ln1g + l * 512, ln1b + l * 512,
                                         h_f32, h_bf);
    mgemm<1, 1, 0><<<dim3(16, 32), 256, 0, stream>>>(
        h_bf, W1B, b1 + (size_t)l * 2048, nullptr, ff1_bf, nullptr, 4096, 2048, 512);
    mgemm<0, 0, 0><<<dim3(4, 32), 256, 0, stream>>>(
        ff1_bf, W2B, b2 + (size_t)l * 512, projf, nullptr, nullptr, 4096, 512, 2048);
    residual_ln<<<4096, 64, 0, stream>>>(projf, h_f32, ln2g + l * 512, ln2b + l * 512,
                                         h_f32, h_bf);
  }

  // ---- gated pooling (stage 1: fused tanh/sigmoid GEMM, N=256) ----
  float* G    = R2f;              // 4096 x 256
  float* A1   = R2f + 1048576;
  float* out1 = R2f + 1052672;
  float* Gv2  = R2f + 1183744;
  float* Gu2  = R2f + 1216512;
  float* A2   = R2f + 1249280;
  float* out2 = R2f + 1249536;

  mgemm<4, 0, 0><<<dim3(2, 32), 256, 0, stream>>>(
      h_bf, WvuB, biasG, G, nullptr, nullptr, 4096, 256, 512);
  gate_dot<<<4096, 128, 0, stream>>>(G, G + 128, 256, Ww1, bw1, A1);
  seg_pool<<<256, 256, 0, stream>>>(A1, h_f32, out_f + 64, out1, 16);

  // h_f32 is dead now -> cast Wf1 into its storage (stream-ordered after seg_pool)
  {
    CastJobs J{};
    J.src[0] = Wf1; J.dst[0] = Wf1B; J.n4[0] = 1048576;
    J.njobs = 1;
    cast_multi<<<512, 256, 0, stream>>>(J);
  }

  gemm_bias<2><<<dim3(2, 4), 256, 0, stream>>>(out1, Wv2, bv2, Gv2, 256, 128, 512);
  gemm_bias<3><<<dim3(2, 4), 256, 0, stream>>>(out1, Wu2, bu2, Gu2, 256, 128, 512);
  gate_dot<<<256, 128, 0, stream>>>(Gv2, Gu2, 128, Ww2, bw2, A2);
  seg_pool<<<32, 256, 0, stream>>>(A2, out1, out_f + 4160, out2, 8);

  // ---- CNN head, channels-last ----
  unsigned short* c1T = (unsigned short*)(R2f + 1310720);  // 2,097,152 ush
  unsigned short* c2T = (unsigned short*)(R2f + 2359296);  // 2,097,152 ush
  unsigned short* p2T = (unsigned short*)(R2f + 3407872);  // 1,048,576 ush
  float* c3T = R2f + 3932160;                              // 1,048,576 f
  unsigned short* p3B = (unsigned short*)(R2f + 4980736);  // 524,288 ush (262,144 f)
  float* pt  = R2f + 5242880;                              // 524,288 f
  float* f1  = R2f + 5767168;                              // 8,192 f
  float* f2  = R2f + 5775360;                              // 4,096 f

  conv1_bnT<<<8192, 256, 0, stream>>>(out2, Kc1, bc1, gc1, bb1, c1T);
  convT_mfma<5, 2, 512, 0><<<dim3(16, 32), 256, 0, stream>>>(
      c1T, Wr2B, bc2, gc2, bb2, c2T, nullptr);
  avgpool2_bf<<<1024, 256, 0, stream>>>(c2T, p2T, 256, 262144);
  convT_mfma<7, 3, 256, 1><<<dim3(8, 32), 256, 0, stream>>>(
      p2T, Wr3B, bc3, gc3, bb3, nullptr, c3T);
  pool3_transpose_bf<<<2048, 256, 0, stream>>>(c3T, p3B);
  fc1_mfma<<<128, 256, 0, stream>>>(p3B, Wf1B, pt);
  fc1_reduce<<<32, 256, 0, stream>>>(pt, bf1, g4, b4, f1);
  fc2_kernel<<<4096, 256, 0, stream>>>(f1, Wf2, bf2, g5, b5, f2);
  fc3_kernel<<<1, 64, 0, stream>>>(f2, Wf3, bf3, out_f);
}